// Round 1
// 3293.134 us; speedup vs baseline: 1.5620x; 1.5620x over previous
//
#include <hip/hip_runtime.h>

#define N_NODES 50000
#define N_EDGES 800000
#define N_GRAPHS 512
#define D_IN 128
#define D_EDGE 32
#define D_HID 128
#define D_GLOB 64

__device__ __forceinline__ int clampi(int v, int hi) {   // [0, hi)
    return v < 0 ? 0 : (v >= hi ? hi - 1 : v);
}

// ---------------------------------------------------------------------------
// Counting-sort of edges by destination node.
// counts[50000] -> hist; cursor[50000] -> exclusive prefix; perm[800000].
// ---------------------------------------------------------------------------
__global__ void hist_kernel(const int* __restrict__ eidx, int* __restrict__ counts)
{
    int e = blockIdx.x * 256 + threadIdx.x;
    if (e < N_EDGES) atomicAdd(&counts[clampi(eidx[N_EDGES + e], N_NODES)], 1);
}

__global__ __launch_bounds__(256) void scan_kernel(const int* __restrict__ counts,
                                                   int* __restrict__ cursor)
{
    __shared__ int part[256];
    const int t = threadIdx.x;
    const int chunk = (N_NODES + 255) / 256;          // 196
    int lo = t * chunk;
    int hi = lo + chunk; if (hi > N_NODES) hi = N_NODES;
    int s = 0;
    for (int i = lo; i < hi; ++i) s += counts[i];
    part[t] = s;
    __syncthreads();
    if (t == 0) {
        int run = 0;
        for (int i = 0; i < 256; ++i) { int v = part[i]; part[i] = run; run += v; }
    }
    __syncthreads();
    int run = part[t];
    for (int i = lo; i < hi; ++i) { cursor[i] = run; run += counts[i]; }
}

__global__ void scatter_kernel(const int* __restrict__ eidx,
                               int* __restrict__ cursor, int* __restrict__ perm)
{
    int e = blockIdx.x * 256 + threadIdx.x;
    if (e < N_EDGES) {
        int d = clampi(eidx[N_EDGES + e], N_NODES);
        int p = atomicAdd(&cursor[d], 1);
        perm[p] = e;
    }
}

// ---------------------------------------------------------------------------
// Sorted edge kernel: 32 dest-sorted edges/block, 256 threads.
// Gather [src|dest|attr] rows to LDS, MLP 288->128 relu ->128 relu, stage msg
// in LDS, then segmented reduction over same-dest runs:
//   - runs fully inside the block: plain store (exclusive owner of that dest)
//   - first/last run cut by the block boundary: fp32 atomics (rare)
// sW is stored granule-swizzled: position = (g>>1) | ((g&1)<<4) so both
// ds_read_b128 (sW[k][tx*4], sW[k][64+tx*4]) are 2-way bank access (free).
// ---------------------------------------------------------------------------
__global__ __launch_bounds__(256) void edge_kernel_sorted(
    const float* __restrict__ x, const int* __restrict__ eidx,
    const float* __restrict__ eattr, const int* __restrict__ perm,
    const float* __restrict__ We1, const float* __restrict__ be1,
    const float* __restrict__ We2, const float* __restrict__ be2,
    float* __restrict__ agg)
{
    __shared__ alignas(16) float sA[32][292];   // 288 + 4 pad
    __shared__ alignas(16) float sW[32][128];   // granule-swizzled
    __shared__ alignas(16) float sH[32][133];   // 133: scalar stores 4-way not 16-way
    __shared__ alignas(16) float sRed[128];
    __shared__ int sEdge[32], sSrc[32], sDest[32];
    __shared__ int sRuns[33];
    __shared__ int sNRuns, sAtomF, sAtomL;

    const int tid = threadIdx.x;
    const int tx = tid & 15;
    const int ty = tid >> 4;
    const int e0 = blockIdx.x * 32;

    if (tid < 32) {
        int e = perm[e0 + tid];
        sEdge[tid] = e;
        sSrc[tid]  = clampi(eidx[e], N_NODES);
        sDest[tid] = clampi(eidx[N_EDGES + e], N_NODES);
    }
    __syncthreads();
    if (tid == 0) {
        int n = 0;
        for (int r = 0; r < 32; ++r)
            if (r == 0 || sDest[r] != sDest[r - 1]) sRuns[n++] = r;
        sRuns[n] = 32;
        sNRuns = n;
        int dprev = (e0 > 0) ? clampi(eidx[N_EDGES + perm[e0 - 1]], N_NODES) : -1;
        int dnext = (e0 + 32 < N_EDGES) ? clampi(eidx[N_EDGES + perm[e0 + 32]], N_NODES) : -1;
        sAtomF = (dprev == sDest[0])  ? 1 : 0;
        sAtomL = (dnext == sDest[31]) ? 1 : 0;
    }

    // gather: 32 edges x 72 float4 (32 src + 32 dest + 8 attr) = 2304 = 9*256
    #pragma unroll
    for (int it = 0; it < 9; ++it) {
        int idx = it * 256 + tid;
        int e = idx / 72;
        int c = idx - e * 72;
        const float* p;
        if (c < 32)      p = x + (size_t)sSrc[e] * 128 + c * 4;
        else if (c < 64) p = x + (size_t)sDest[e] * 128 + (c - 32) * 4;
        else             p = eattr + (size_t)sEdge[e] * 32 + (c - 64) * 4;
        *(float4*)&sA[e][c * 4] = *(const float4*)p;
    }

    float acc[2][8];
    #pragma unroll
    for (int i = 0; i < 2; ++i)
        #pragma unroll
        for (int j = 0; j < 8; ++j) acc[i][j] = 0.f;

    // ---- layer 1: K = 288 (9 chunks of 32) ----
    for (int kc = 0; kc < 9; ++kc) {
        __syncthreads();
        #pragma unroll
        for (int it = 0; it < 4; ++it) {
            int idx = it * 256 + tid;
            int r = idx >> 5, c4 = idx & 31;
            int p = (c4 >> 1) | ((c4 & 1) << 4);
            *(float4*)&sW[r][p * 4] = *(const float4*)&We1[(size_t)(kc * 32 + r) * 128 + c4 * 4];
        }
        __syncthreads();
        #pragma unroll
        for (int k = 0; k < 32; ++k) {
            float4 w0 = *(float4*)&sW[k][tx * 4];
            float4 w1 = *(float4*)&sW[k][64 + tx * 4];
            float w[8] = {w0.x, w0.y, w0.z, w0.w, w1.x, w1.y, w1.z, w1.w};
            float a0 = sA[ty * 2 + 0][kc * 32 + k];
            float a1 = sA[ty * 2 + 1][kc * 32 + k];
            #pragma unroll
            for (int j = 0; j < 8; ++j) {
                acc[0][j] = fmaf(a0, w[j], acc[0][j]);
                acc[1][j] = fmaf(a1, w[j], acc[1][j]);
            }
        }
    }

    // bias + relu -> sH, reset acc
    #pragma unroll
    for (int j = 0; j < 8; ++j) {
        float b = be1[tx * 8 + j];
        #pragma unroll
        for (int i = 0; i < 2; ++i) {
            sH[ty * 2 + i][tx * 8 + j] = fmaxf(acc[i][j] + b, 0.f);
            acc[i][j] = 0.f;
        }
    }

    // ---- layer 2: K = 128 (4 chunks of 32) ----
    for (int kc = 0; kc < 4; ++kc) {
        __syncthreads();
        #pragma unroll
        for (int it = 0; it < 4; ++it) {
            int idx = it * 256 + tid;
            int r = idx >> 5, c4 = idx & 31;
            int p = (c4 >> 1) | ((c4 & 1) << 4);
            *(float4*)&sW[r][p * 4] = *(const float4*)&We2[(size_t)(kc * 32 + r) * 128 + c4 * 4];
        }
        __syncthreads();
        #pragma unroll
        for (int k = 0; k < 32; ++k) {
            float4 w0 = *(float4*)&sW[k][tx * 4];
            float4 w1 = *(float4*)&sW[k][64 + tx * 4];
            float w[8] = {w0.x, w0.y, w0.z, w0.w, w1.x, w1.y, w1.z, w1.w};
            float a0 = sH[ty * 2 + 0][kc * 32 + k];
            float a1 = sH[ty * 2 + 1][kc * 32 + k];
            #pragma unroll
            for (int j = 0; j < 8; ++j) {
                acc[0][j] = fmaf(a0, w[j], acc[0][j]);
                acc[1][j] = fmaf(a1, w[j], acc[1][j]);
            }
        }
    }

    // stage msg rows (bias + relu) into sH, then segmented reduce per run
    __syncthreads();   // everyone done reading sH in layer 2
    #pragma unroll
    for (int j = 0; j < 8; ++j) {
        float b = be2[tx * 8 + j];
        #pragma unroll
        for (int i = 0; i < 2; ++i)
            sH[ty * 2 + i][tx * 8 + j] = fmaxf(acc[i][j] + b, 0.f);
    }
    __syncthreads();

    const int c = tid & 127;
    const int h = tid >> 7;
    const int nR = sNRuns;
    for (int m = 0; m < nR; ++m) {
        int s = sRuns[m], epos = sRuns[m + 1];
        float part = 0.f;
        for (int r = s + h; r < epos; r += 2) part += sH[r][c];
        if (h) sRed[c] = part;
        __syncthreads();
        if (!h) {
            float v = part + sRed[c];
            int d = sDest[s];
            float* dst = agg + (size_t)d * 128 + c;
            bool atom = (m == 0 && sAtomF) || (m == nR - 1 && sAtomL);
            if (atom) unsafeAtomicAdd(dst, v);
            else      *dst = v;        // exclusive owner of this dest
        }
        __syncthreads();
    }
}

// ---------------------------------------------------------------------------
// Fallback edge kernel (original): full atomic scatter. Used only when the
// workspace is too small for the counting sort.
// ---------------------------------------------------------------------------
__global__ __launch_bounds__(256) void edge_kernel(
    const float* __restrict__ x, const int* __restrict__ eidx,
    const float* __restrict__ eattr,
    const float* __restrict__ We1, const float* __restrict__ be1,
    const float* __restrict__ We2, const float* __restrict__ be2,
    float* __restrict__ agg)
{
    __shared__ alignas(16) float sA[32][292];
    __shared__ alignas(16) float sW[32][128];
    __shared__ alignas(16) float sH[32][132];
    __shared__ int sDest[32];

    const int tid = threadIdx.x;
    const int tx = tid & 15;
    const int ty = tid >> 4;
    const int e0 = blockIdx.x * 32;

    if (tid < 32) sDest[tid] = clampi(eidx[N_EDGES + e0 + tid], N_NODES);

    #pragma unroll
    for (int it = 0; it < 9; ++it) {
        int idx = it * 256 + tid;
        int e = idx / 72;
        int c = idx - e * 72;
        const float* p;
        if (c < 32)      p = x + (size_t)clampi(eidx[e0 + e], N_NODES) * 128 + c * 4;
        else if (c < 64) p = x + (size_t)clampi(eidx[N_EDGES + e0 + e], N_NODES) * 128 + (c - 32) * 4;
        else             p = eattr + (size_t)(e0 + e) * 32 + (c - 64) * 4;
        *(float4*)&sA[e][c * 4] = *(const float4*)p;
    }

    float acc[2][8];
    #pragma unroll
    for (int i = 0; i < 2; ++i)
        #pragma unroll
        for (int j = 0; j < 8; ++j) acc[i][j] = 0.f;

    for (int kc = 0; kc < 9; ++kc) {
        __syncthreads();
        #pragma unroll
        for (int it = 0; it < 4; ++it) {
            int idx = it * 256 + tid;
            int r = idx >> 5, c4 = idx & 31;
            *(float4*)&sW[r][c4 * 4] = *(const float4*)&We1[(size_t)(kc * 32 + r) * 128 + c4 * 4];
        }
        __syncthreads();
        #pragma unroll
        for (int k = 0; k < 32; ++k) {
            float4 w0 = *(float4*)&sW[k][tx * 8];
            float4 w1 = *(float4*)&sW[k][tx * 8 + 4];
            float w[8] = {w0.x, w0.y, w0.z, w0.w, w1.x, w1.y, w1.z, w1.w};
            float a0 = sA[ty * 2 + 0][kc * 32 + k];
            float a1 = sA[ty * 2 + 1][kc * 32 + k];
            #pragma unroll
            for (int j = 0; j < 8; ++j) {
                acc[0][j] = fmaf(a0, w[j], acc[0][j]);
                acc[1][j] = fmaf(a1, w[j], acc[1][j]);
            }
        }
    }

    #pragma unroll
    for (int j = 0; j < 8; ++j) {
        float b = be1[tx * 8 + j];
        #pragma unroll
        for (int i = 0; i < 2; ++i) {
            sH[ty * 2 + i][tx * 8 + j] = fmaxf(acc[i][j] + b, 0.f);
            acc[i][j] = 0.f;
        }
    }

    for (int kc = 0; kc < 4; ++kc) {
        __syncthreads();
        #pragma unroll
        for (int it = 0; it < 4; ++it) {
            int idx = it * 256 + tid;
            int r = idx >> 5, c4 = idx & 31;
            *(float4*)&sW[r][c4 * 4] = *(const float4*)&We2[(size_t)(kc * 32 + r) * 128 + c4 * 4];
        }
        __syncthreads();
        #pragma unroll
        for (int k = 0; k < 32; ++k) {
            float4 w0 = *(float4*)&sW[k][tx * 8];
            float4 w1 = *(float4*)&sW[k][tx * 8 + 4];
            float w[8] = {w0.x, w0.y, w0.z, w0.w, w1.x, w1.y, w1.z, w1.w};
            float a0 = sH[ty * 2 + 0][kc * 32 + k];
            float a1 = sH[ty * 2 + 1][kc * 32 + k];
            #pragma unroll
            for (int j = 0; j < 8; ++j) {
                acc[0][j] = fmaf(a0, w[j], acc[0][j]);
                acc[1][j] = fmaf(a1, w[j], acc[1][j]);
            }
        }
    }

    #pragma unroll
    for (int i = 0; i < 2; ++i) {
        int d = sDest[ty * 2 + i];
        float* dst = agg + (size_t)d * 128 + tx * 8;
        #pragma unroll
        for (int j = 0; j < 8; ++j) {
            float b = be2[tx * 8 + j];
            float v = fmaxf(acc[i][j] + b, 0.f);
            unsafeAtomicAdd(dst + j, v);
        }
    }
}

// ---------------------------------------------------------------------------
// Fused node+global kernel (unchanged): one block (256 threads) per graph.
// ---------------------------------------------------------------------------
__global__ __launch_bounds__(256) void node_global_kernel(
    const float* __restrict__ x, const float* __restrict__ agg,
    const int* __restrict__ batch,
    const float* __restrict__ Wg, const float* __restrict__ bg,
    const float* __restrict__ Wn, const float* __restrict__ bn,
    const float* __restrict__ u, const float* __restrict__ Wu,
    const float* __restrict__ bu,
    float* __restrict__ xw_out, float* __restrict__ out)
{
    __shared__ alignas(16) float sA[32][260];
    __shared__ alignas(16) float sW[32][128];
    __shared__ alignas(16) float redu[16][132];
    __shared__ alignas(16) float cat[192];
    __shared__ int sRange[2];

    const int tid = threadIdx.x;
    const int tx = tid & 15;
    const int ty = tid >> 4;
    const int g = blockIdx.x;

    if (tid == 0) {
        int lo = 0, hi = N_NODES;
        while (lo < hi) { int m = (lo + hi) >> 1; if (batch[m] < g) lo = m + 1; else hi = m; }
        sRange[0] = lo;
        hi = N_NODES;
        while (lo < hi) { int m = (lo + hi) >> 1; if (batch[m] < g + 1) lo = m + 1; else hi = m; }
        sRange[1] = lo;
    }
    __syncthreads();
    const int start = sRange[0];
    const int end   = sRange[1];

    float pool_acc[8];
    #pragma unroll
    for (int j = 0; j < 8; ++j) pool_acc[j] = 0.f;

    for (int n0 = start; n0 < end; n0 += 32) {
        #pragma unroll
        for (int it = 0; it < 4; ++it) {
            int idx = it * 256 + tid;
            int r = idx >> 5, c = idx & 31;
            float4 v = make_float4(0.f, 0.f, 0.f, 0.f);
            if (n0 + r < end) v = *(const float4*)&x[(size_t)(n0 + r) * 128 + c * 4];
            *(float4*)&sA[r][c * 4] = v;
        }
        #pragma unroll
        for (int it = 0; it < 4; ++it) {
            int idx = it * 256 + tid;
            int r = idx >> 5, c = idx & 31;
            float4 v = make_float4(0.f, 0.f, 0.f, 0.f);
            if (n0 + r < end) v = *(const float4*)&agg[(size_t)(n0 + r) * 128 + c * 4];
            *(float4*)&sA[r][128 + c * 4] = v;
        }

        float acc[2][8];
        #pragma unroll
        for (int i = 0; i < 2; ++i)
            #pragma unroll
            for (int j = 0; j < 8; ++j) acc[i][j] = 0.f;

        for (int kc = 0; kc < 8; ++kc) {
            __syncthreads();
            #pragma unroll
            for (int it = 0; it < 4; ++it) {
                int idx = it * 256 + tid;
                int r = idx >> 5, c4 = idx & 31;
                *(float4*)&sW[r][c4 * 4] = *(const float4*)&Wg[(size_t)(kc * 32 + r) * 128 + c4 * 4];
            }
            __syncthreads();
            #pragma unroll
            for (int k = 0; k < 32; ++k) {
                float4 w0 = *(float4*)&sW[k][tx * 8];
                float4 w1 = *(float4*)&sW[k][tx * 8 + 4];
                float w[8] = {w0.x, w0.y, w0.z, w0.w, w1.x, w1.y, w1.z, w1.w};
                float a0 = sA[ty * 2 + 0][kc * 32 + k];
                float a1 = sA[ty * 2 + 1][kc * 32 + k];
                #pragma unroll
                for (int j = 0; j < 8; ++j) {
                    acc[0][j] = fmaf(a0, w[j], acc[0][j]);
                    acc[1][j] = fmaf(a1, w[j], acc[1][j]);
                }
            }
        }

        float gate[2][8];
        #pragma unroll
        for (int i = 0; i < 2; ++i) {
            int n = n0 + ty * 2 + i;
            #pragma unroll
            for (int j = 0; j < 8; ++j) {
                float v = acc[i][j] + bg[tx * 8 + j];
                gate[i][j] = 1.0f / (1.0f + __expf(-v));
                acc[i][j] = 0.f;
            }
            if (n < end) {
                float4 g0 = make_float4(gate[i][0], gate[i][1], gate[i][2], gate[i][3]);
                float4 g1 = make_float4(gate[i][4], gate[i][5], gate[i][6], gate[i][7]);
                *(float4*)&xw_out[(size_t)n * 128 + tx * 8]     = g0;
                *(float4*)&xw_out[(size_t)n * 128 + tx * 8 + 4] = g1;
            }
        }

        for (int kc = 0; kc < 8; ++kc) {
            __syncthreads();
            #pragma unroll
            for (int it = 0; it < 4; ++it) {
                int idx = it * 256 + tid;
                int r = idx >> 5, c4 = idx & 31;
                *(float4*)&sW[r][c4 * 4] = *(const float4*)&Wn[(size_t)(kc * 32 + r) * 128 + c4 * 4];
            }
            __syncthreads();
            #pragma unroll
            for (int k = 0; k < 32; ++k) {
                float4 w0 = *(float4*)&sW[k][tx * 8];
                float4 w1 = *(float4*)&sW[k][tx * 8 + 4];
                float w[8] = {w0.x, w0.y, w0.z, w0.w, w1.x, w1.y, w1.z, w1.w};
                float a0 = sA[ty * 2 + 0][kc * 32 + k];
                float a1 = sA[ty * 2 + 1][kc * 32 + k];
                #pragma unroll
                for (int j = 0; j < 8; ++j) {
                    acc[0][j] = fmaf(a0, w[j], acc[0][j]);
                    acc[1][j] = fmaf(a1, w[j], acc[1][j]);
                }
            }
        }

        #pragma unroll
        for (int i = 0; i < 2; ++i) {
            int n = n0 + ty * 2 + i;
            if (n < end) {
                #pragma unroll
                for (int j = 0; j < 8; ++j) {
                    float v = fmaxf(acc[i][j] + bn[tx * 8 + j], 0.f);
                    pool_acc[j] += gate[i][j] * v;
                }
            }
        }
        __syncthreads();
    }

    #pragma unroll
    for (int j = 0; j < 8; ++j) redu[ty][tx * 8 + j] = pool_acc[j];
    __syncthreads();
    #pragma unroll
    for (int s = 8; s >= 1; s >>= 1) {
        if (ty < s) {
            #pragma unroll
            for (int j = 0; j < 8; ++j)
                redu[ty][tx * 8 + j] += redu[ty + s][tx * 8 + j];
        }
        __syncthreads();
    }

    float cnt = fmaxf((float)(end - start), 1.0f);
    if (tid < 64)        cat[tid] = u[g * 64 + tid];
    else if (tid < 192)  cat[tid] = redu[0][tid - 64] / cnt;
    __syncthreads();
    if (tid < 64) {
        float acc = bu[tid];
        #pragma unroll 4
        for (int k = 0; k < 192; ++k)
            acc = fmaf(cat[k], Wu[k * 64 + tid], acc);
        out[g * 64 + tid] = fmaxf(acc, 0.f);
    }
}

// ---------------------------------------------------------------------------
extern "C" void kernel_launch(void* const* d_in, const int* in_sizes, int n_in,
                              void* d_out, int out_size, void* d_ws, size_t ws_size,
                              hipStream_t stream) {
    const float* x     = (const float*)d_in[0];
    const int*   eidx  = (const int*)d_in[1];
    const float* eattr = (const float*)d_in[2];
    const float* u     = (const float*)d_in[3];
    const int*   batch = (const int*)d_in[4];
    const float* We1   = (const float*)d_in[5];
    const float* be1   = (const float*)d_in[6];
    const float* We2   = (const float*)d_in[7];
    const float* be2   = (const float*)d_in[8];
    const float* Wg    = (const float*)d_in[9];
    const float* bg    = (const float*)d_in[10];
    const float* Wn    = (const float*)d_in[11];
    const float* bn    = (const float*)d_in[12];
    const float* Wu    = (const float*)d_in[13];
    const float* bu    = (const float*)d_in[14];

    float* out    = (float*)d_out;                 // chunk 0: u_new [512*64] fp32
    float* xw_out = out + N_GRAPHS * D_GLOB;       // chunk 1: x_weights [50000*128] fp32
    float* agg    = xw_out;                        // fp32 agg aliases chunk 1

    // zero the agg region (d_out is re-poisoned before every timed launch)
    hipMemsetAsync(xw_out, 0, (size_t)N_NODES * D_HID * sizeof(float), stream);

    const size_t wsNeeded = (size_t)(2 * N_NODES + N_EDGES) * sizeof(int);  // ~3.6 MB
    if (d_ws != nullptr && ws_size >= wsNeeded) {
        int* counts = (int*)d_ws;
        int* cursor = counts + N_NODES;
        int* perm   = cursor + N_NODES;
        hipMemsetAsync(counts, 0, (size_t)N_NODES * sizeof(int), stream);
        hist_kernel<<<(N_EDGES + 255) / 256, 256, 0, stream>>>(eidx, counts);
        scan_kernel<<<1, 256, 0, stream>>>(counts, cursor);
        scatter_kernel<<<(N_EDGES + 255) / 256, 256, 0, stream>>>(eidx, cursor, perm);
        edge_kernel_sorted<<<N_EDGES / 32, 256, 0, stream>>>(x, eidx, eattr, perm,
                                                             We1, be1, We2, be2, agg);
    } else {
        edge_kernel<<<N_EDGES / 32, 256, 0, stream>>>(x, eidx, eattr, We1, be1, We2, be2, agg);
    }
    node_global_kernel<<<N_GRAPHS, 256, 0, stream>>>(x, agg, batch, Wg, bg, Wn, bn,
                                                     u, Wu, bu, xw_out, out);
}

// Round 2
// 3291.773 us; speedup vs baseline: 1.5626x; 1.0004x over previous
//
#include <hip/hip_runtime.h>

#define N_NODES 50000
#define N_EDGES 800000
#define N_GRAPHS 512
#define D_IN 128
#define D_EDGE 32
#define D_HID 128
#define D_GLOB 64
#define NTILES (N_EDGES / 256)   // 3125

__device__ __forceinline__ int clampi(int v, int hi) {   // [0, hi)
    return v < 0 ? 0 : (v >= hi ? hi - 1 : v);
}

// ---------------------------------------------------------------------------
// Counting-sort of edges by destination node.
// ---------------------------------------------------------------------------
__global__ void hist_kernel(const int* __restrict__ eidx, int* __restrict__ counts)
{
    int e = blockIdx.x * 256 + threadIdx.x;
    if (e < N_EDGES) atomicAdd(&counts[clampi(eidx[N_EDGES + e], N_NODES)], 1);
}

__global__ __launch_bounds__(256) void scan_kernel(const int* __restrict__ counts,
                                                   int* __restrict__ cursor)
{
    __shared__ int part[256];
    const int t = threadIdx.x;
    const int chunk = (N_NODES + 255) / 256;          // 196
    int lo = t * chunk;
    int hi = lo + chunk; if (hi > N_NODES) hi = N_NODES;
    int s = 0;
    for (int i = lo; i < hi; ++i) s += counts[i];
    part[t] = s;
    __syncthreads();
    if (t == 0) {
        int run = 0;
        for (int i = 0; i < 256; ++i) { int v = part[i]; part[i] = run; run += v; }
    }
    __syncthreads();
    int run = part[t];
    for (int i = lo; i < hi; ++i) { cursor[i] = run; run += counts[i]; }
}

__global__ void scatter_kernel(const int* __restrict__ eidx,
                               int* __restrict__ cursor, int* __restrict__ perm)
{
    int e = blockIdx.x * 256 + threadIdx.x;
    if (e < N_EDGES) {
        int d = clampi(eidx[N_EDGES + e], N_NODES);
        int p = atomicAdd(&cursor[d], 1);
        perm[p] = e;
    }
}

// ---------------------------------------------------------------------------
// Register-tile GEMM core: 256 threads, tx = tid&7 owns cols {q*32+tx*4+j},
// ty = tid>>3 owns 8 rows. A operand comes straight from global memory into
// double-buffered registers (no LDS); W is LDS-resident, read 4xb128 per k
// hitting all 32 banks (conflict-free).
// ---------------------------------------------------------------------------
template<int KBASE>
__device__ __forceinline__ void step4(const float* __restrict__ sW, int kg, int tx,
                                      const float4 (&a)[8], float (&acc)[8][16])
{
    #pragma unroll
    for (int kk = 0; kk < 4; ++kk) {
        const float* wr = sW + (size_t)(KBASE + kg * 4 + kk) * 128 + tx * 4;
        float4 w0 = *(const float4*)(wr);
        float4 w1 = *(const float4*)(wr + 32);
        float4 w2 = *(const float4*)(wr + 64);
        float4 w3 = *(const float4*)(wr + 96);
        #pragma unroll
        for (int r = 0; r < 8; ++r) {
            const float av = ((const float*)&a[r])[kk];
            acc[r][0]  = fmaf(av, w0.x, acc[r][0]);
            acc[r][1]  = fmaf(av, w0.y, acc[r][1]);
            acc[r][2]  = fmaf(av, w0.z, acc[r][2]);
            acc[r][3]  = fmaf(av, w0.w, acc[r][3]);
            acc[r][4]  = fmaf(av, w1.x, acc[r][4]);
            acc[r][5]  = fmaf(av, w1.y, acc[r][5]);
            acc[r][6]  = fmaf(av, w1.z, acc[r][6]);
            acc[r][7]  = fmaf(av, w1.w, acc[r][7]);
            acc[r][8]  = fmaf(av, w2.x, acc[r][8]);
            acc[r][9]  = fmaf(av, w2.y, acc[r][9]);
            acc[r][10] = fmaf(av, w2.z, acc[r][10]);
            acc[r][11] = fmaf(av, w2.w, acc[r][11]);
            acc[r][12] = fmaf(av, w3.x, acc[r][12]);
            acc[r][13] = fmaf(av, w3.y, acc[r][13]);
            acc[r][14] = fmaf(av, w3.z, acc[r][14]);
            acc[r][15] = fmaf(av, w3.w, acc[r][15]);
        }
    }
}

template<int KBASE, int KG>
__device__ __forceinline__ void gemm_seg(const float* __restrict__ sW, int tx,
                                         const float* const (&bp)[8],
                                         float (&acc)[8][16])
{
    float4 a0[8], a1[8];
    #pragma unroll
    for (int r = 0; r < 8; ++r) a0[r] = *(const float4*)(bp[r]);
    #pragma unroll 1
    for (int kg = 0; kg < KG; kg += 2) {
        #pragma unroll
        for (int r = 0; r < 8; ++r) a1[r] = *(const float4*)(bp[r] + (kg + 1) * 4);
        step4<KBASE>(sW, kg, tx, a0, acc);
        if (kg + 2 < KG) {
            #pragma unroll
            for (int r = 0; r < 8; ++r) a0[r] = *(const float4*)(bp[r] + (kg + 2) * 4);
        }
        step4<KBASE>(sW, kg + 1, tx, a1, acc);
    }
}

// ---------------------------------------------------------------------------
// Edge layer-1 kernel: We1 (288x128 = 147 KB) resident in LDS for the whole
// (persistent) block. Per 256-edge tile: gather A rows direct-to-register
// from global, GEMM K=288 with zero k-loop barriers, write h to workspace.
// ---------------------------------------------------------------------------
__global__ __launch_bounds__(256) void edge_l1_kernel(
    const float* __restrict__ x, const int* __restrict__ eidx,
    const float* __restrict__ eattr, const int* __restrict__ perm,
    const float* __restrict__ We1, const float* __restrict__ be1,
    float* __restrict__ h_ws)
{
    __shared__ float sW[288 * 128];          // 147456 B
    __shared__ int sSrc[256], sDst[256], sEdg[256];

    const int tid = threadIdx.x;
    const int tx = tid & 7;
    const int ty = tid >> 3;

    #pragma unroll 4
    for (int it = 0; it < 144; ++it)
        ((float4*)sW)[it * 256 + tid] = ((const float4*)We1)[it * 256 + tid];

    for (int t = blockIdx.x; t < NTILES; t += gridDim.x) {
        const int e0 = t * 256;
        __syncthreads();                     // sW ready / prior tile idx reads done
        {
            int p = perm[e0 + tid];
            sEdg[tid] = p;
            sSrc[tid] = clampi(eidx[p], N_NODES);
            sDst[tid] = clampi(eidx[N_EDGES + p], N_NODES);
        }
        __syncthreads();

        float acc[8][16];
        #pragma unroll
        for (int r = 0; r < 8; ++r)
            #pragma unroll
            for (int c = 0; c < 16; ++c) acc[r][c] = 0.f;

        {
            const float* bp[8];
            #pragma unroll
            for (int r = 0; r < 8; ++r) bp[r] = x + (size_t)sSrc[ty * 8 + r] * 128;
            gemm_seg<0, 32>(sW, tx, bp, acc);
        }
        {
            const float* bp[8];
            #pragma unroll
            for (int r = 0; r < 8; ++r) bp[r] = x + (size_t)sDst[ty * 8 + r] * 128;
            gemm_seg<128, 32>(sW, tx, bp, acc);
        }
        {
            const float* bp[8];
            #pragma unroll
            for (int r = 0; r < 8; ++r) bp[r] = eattr + (size_t)sEdg[ty * 8 + r] * 32;
            gemm_seg<256, 8>(sW, tx, bp, acc);
        }

        const float4 b0 = *(const float4*)&be1[ 0 + tx * 4];
        const float4 b1 = *(const float4*)&be1[32 + tx * 4];
        const float4 b2 = *(const float4*)&be1[64 + tx * 4];
        const float4 b3 = *(const float4*)&be1[96 + tx * 4];
        #pragma unroll
        for (int r = 0; r < 8; ++r) {
            float* dst = h_ws + (size_t)(e0 + ty * 8 + r) * 128 + tx * 4;
            float4 v;
            v.x = fmaxf(acc[r][0]  + b0.x, 0.f); v.y = fmaxf(acc[r][1]  + b0.y, 0.f);
            v.z = fmaxf(acc[r][2]  + b0.z, 0.f); v.w = fmaxf(acc[r][3]  + b0.w, 0.f);
            *(float4*)(dst) = v;
            v.x = fmaxf(acc[r][4]  + b1.x, 0.f); v.y = fmaxf(acc[r][5]  + b1.y, 0.f);
            v.z = fmaxf(acc[r][6]  + b1.z, 0.f); v.w = fmaxf(acc[r][7]  + b1.w, 0.f);
            *(float4*)(dst + 32) = v;
            v.x = fmaxf(acc[r][8]  + b2.x, 0.f); v.y = fmaxf(acc[r][9]  + b2.y, 0.f);
            v.z = fmaxf(acc[r][10] + b2.z, 0.f); v.w = fmaxf(acc[r][11] + b2.w, 0.f);
            *(float4*)(dst + 64) = v;
            v.x = fmaxf(acc[r][12] + b3.x, 0.f); v.y = fmaxf(acc[r][13] + b3.y, 0.f);
            v.z = fmaxf(acc[r][14] + b3.z, 0.f); v.w = fmaxf(acc[r][15] + b3.w, 0.f);
            *(float4*)(dst + 96) = v;
        }
    }
}

// ---------------------------------------------------------------------------
// Edge layer-2 + scatter kernel: We2 (64 KB) LDS-resident, persistent blocks.
// GEMM K=128 on contiguous h rows; epilogue stages 64-row msg subtiles in LDS
// and segment-reduces per dest run (one wave per run, no per-run barriers);
// atomics only where a run crosses a subtile boundary.
// ---------------------------------------------------------------------------
__global__ __launch_bounds__(256) void edge_l2_kernel(
    const float* __restrict__ h_ws, const int* __restrict__ eidx,
    const int* __restrict__ perm,
    const float* __restrict__ We2, const float* __restrict__ be2,
    float* __restrict__ agg)
{
    __shared__ float sW[128 * 128];          // 65536 B
    __shared__ float sRed[64][132];          // 33792 B
    __shared__ int sDest[256];
    __shared__ int sRunS[4][65];
    __shared__ int sNR[4], sAF[4], sAL[4];

    const int tid = threadIdx.x;
    const int tx = tid & 7;
    const int ty = tid >> 3;
    const int wid = tid >> 6;
    const int lane = tid & 63;

    #pragma unroll 4
    for (int it = 0; it < 64; ++it)
        ((float4*)sW)[it * 256 + tid] = ((const float4*)We2)[it * 256 + tid];

    const float4 c0 = *(const float4*)&be2[ 0 + tx * 4];
    const float4 c1 = *(const float4*)&be2[32 + tx * 4];
    const float4 c2 = *(const float4*)&be2[64 + tx * 4];
    const float4 c3 = *(const float4*)&be2[96 + tx * 4];

    for (int t = blockIdx.x; t < NTILES; t += gridDim.x) {
        const int e0 = t * 256;
        __syncthreads();                     // sW ready / prior tile LDS reads done
        sDest[tid] = clampi(eidx[N_EDGES + perm[e0 + tid]], N_NODES);
        __syncthreads();

        if (tid < 4) {                       // run detection, one lane per subtile
            const int base = tid * 64;
            int prev;
            if (base == 0)
                prev = (e0 > 0) ? clampi(eidx[N_EDGES + perm[e0 - 1]], N_NODES) : -1;
            else
                prev = sDest[base - 1];
            sAF[tid] = (prev == sDest[base]) ? 1 : 0;
            int n = 0;
            for (int i = 0; i < 64; ++i) {
                int d = sDest[base + i];
                if (i == 0 || d != sDest[base + i - 1]) sRunS[tid][n++] = base + i;
            }
            sRunS[tid][n] = base + 64;
            sNR[tid] = n;
            int nxt;
            if (base + 64 == 256)
                nxt = (e0 + 256 < N_EDGES) ? clampi(eidx[N_EDGES + perm[e0 + 256]], N_NODES) : -1;
            else
                nxt = sDest[base + 64];
            sAL[tid] = (nxt == sDest[base + 63]) ? 1 : 0;
        }

        float acc[8][16];
        #pragma unroll
        for (int r = 0; r < 8; ++r)
            #pragma unroll
            for (int c = 0; c < 16; ++c) acc[r][c] = 0.f;

        {
            const float* bp[8];
            #pragma unroll
            for (int r = 0; r < 8; ++r) bp[r] = h_ws + (size_t)(e0 + ty * 8 + r) * 128;
            gemm_seg<0, 32>(sW, tx, bp, acc);
        }

        for (int g4 = 0; g4 < 4; ++g4) {
            __syncthreads();                 // prior subtile reads done / runs ready
            if ((ty >> 3) == g4) {
                const int lr = (ty & 7) * 8;
                #pragma unroll
                for (int r = 0; r < 8; ++r) {
                    float4 v;
                    v.x = fmaxf(acc[r][0]  + c0.x, 0.f); v.y = fmaxf(acc[r][1]  + c0.y, 0.f);
                    v.z = fmaxf(acc[r][2]  + c0.z, 0.f); v.w = fmaxf(acc[r][3]  + c0.w, 0.f);
                    *(float4*)&sRed[lr + r][ 0 + tx * 4] = v;
                    v.x = fmaxf(acc[r][4]  + c1.x, 0.f); v.y = fmaxf(acc[r][5]  + c1.y, 0.f);
                    v.z = fmaxf(acc[r][6]  + c1.z, 0.f); v.w = fmaxf(acc[r][7]  + c1.w, 0.f);
                    *(float4*)&sRed[lr + r][32 + tx * 4] = v;
                    v.x = fmaxf(acc[r][8]  + c2.x, 0.f); v.y = fmaxf(acc[r][9]  + c2.y, 0.f);
                    v.z = fmaxf(acc[r][10] + c2.z, 0.f); v.w = fmaxf(acc[r][11] + c2.w, 0.f);
                    *(float4*)&sRed[lr + r][64 + tx * 4] = v;
                    v.x = fmaxf(acc[r][12] + c3.x, 0.f); v.y = fmaxf(acc[r][13] + c3.y, 0.f);
                    v.z = fmaxf(acc[r][14] + c3.z, 0.f); v.w = fmaxf(acc[r][15] + c3.w, 0.f);
                    *(float4*)&sRed[lr + r][96 + tx * 4] = v;
                }
            }
            __syncthreads();
            const int nR = sNR[g4];
            for (int m = wid; m < nR; m += 4) {   // one wave per run
                const int s = sRunS[g4][m]     - g4 * 64;
                const int e = sRunS[g4][m + 1] - g4 * 64;
                float v0 = 0.f, v1 = 0.f;
                for (int r = s; r < e; ++r) { v0 += sRed[r][lane]; v1 += sRed[r][lane + 64]; }
                const int d = sDest[g4 * 64 + s];
                float* dst = agg + (size_t)d * 128;
                const bool atom = (m == 0 && sAF[g4]) || (m == nR - 1 && sAL[g4]);
                if (atom) {
                    unsafeAtomicAdd(dst + lane,      v0);
                    unsafeAtomicAdd(dst + lane + 64, v1);
                } else {
                    dst[lane]      = v0;         // exclusive owner of this dest
                    dst[lane + 64] = v1;
                }
            }
        }
    }
}

// ---------------------------------------------------------------------------
// Round-1 fallback: fused sorted edge kernel (used when ws fits sort only).
// ---------------------------------------------------------------------------
__global__ __launch_bounds__(256) void edge_kernel_sorted(
    const float* __restrict__ x, const int* __restrict__ eidx,
    const float* __restrict__ eattr, const int* __restrict__ perm,
    const float* __restrict__ We1, const float* __restrict__ be1,
    const float* __restrict__ We2, const float* __restrict__ be2,
    float* __restrict__ agg)
{
    __shared__ alignas(16) float sA[32][292];
    __shared__ alignas(16) float sW[32][128];
    __shared__ alignas(16) float sH[32][133];
    __shared__ alignas(16) float sRed[128];
    __shared__ int sEdge[32], sSrc[32], sDest[32];
    __shared__ int sRuns[33];
    __shared__ int sNRuns, sAtomF, sAtomL;

    const int tid = threadIdx.x;
    const int tx = tid & 15;
    const int ty = tid >> 4;
    const int e0 = blockIdx.x * 32;

    if (tid < 32) {
        int e = perm[e0 + tid];
        sEdge[tid] = e;
        sSrc[tid]  = clampi(eidx[e], N_NODES);
        sDest[tid] = clampi(eidx[N_EDGES + e], N_NODES);
    }
    __syncthreads();
    if (tid == 0) {
        int n = 0;
        for (int r = 0; r < 32; ++r)
            if (r == 0 || sDest[r] != sDest[r - 1]) sRuns[n++] = r;
        sRuns[n] = 32;
        sNRuns = n;
        int dprev = (e0 > 0) ? clampi(eidx[N_EDGES + perm[e0 - 1]], N_NODES) : -1;
        int dnext = (e0 + 32 < N_EDGES) ? clampi(eidx[N_EDGES + perm[e0 + 32]], N_NODES) : -1;
        sAtomF = (dprev == sDest[0])  ? 1 : 0;
        sAtomL = (dnext == sDest[31]) ? 1 : 0;
    }

    #pragma unroll
    for (int it = 0; it < 9; ++it) {
        int idx = it * 256 + tid;
        int e = idx / 72;
        int c = idx - e * 72;
        const float* p;
        if (c < 32)      p = x + (size_t)sSrc[e] * 128 + c * 4;
        else if (c < 64) p = x + (size_t)sDest[e] * 128 + (c - 32) * 4;
        else             p = eattr + (size_t)sEdge[e] * 32 + (c - 64) * 4;
        *(float4*)&sA[e][c * 4] = *(const float4*)p;
    }

    float acc[2][8];
    #pragma unroll
    for (int i = 0; i < 2; ++i)
        #pragma unroll
        for (int j = 0; j < 8; ++j) acc[i][j] = 0.f;

    for (int kc = 0; kc < 9; ++kc) {
        __syncthreads();
        #pragma unroll
        for (int it = 0; it < 4; ++it) {
            int idx = it * 256 + tid;
            int r = idx >> 5, c4 = idx & 31;
            int p = (c4 >> 1) | ((c4 & 1) << 4);
            *(float4*)&sW[r][p * 4] = *(const float4*)&We1[(size_t)(kc * 32 + r) * 128 + c4 * 4];
        }
        __syncthreads();
        #pragma unroll
        for (int k = 0; k < 32; ++k) {
            float4 w0 = *(float4*)&sW[k][tx * 4];
            float4 w1 = *(float4*)&sW[k][64 + tx * 4];
            float w[8] = {w0.x, w0.y, w0.z, w0.w, w1.x, w1.y, w1.z, w1.w};
            float a0 = sA[ty * 2 + 0][kc * 32 + k];
            float a1 = sA[ty * 2 + 1][kc * 32 + k];
            #pragma unroll
            for (int j = 0; j < 8; ++j) {
                acc[0][j] = fmaf(a0, w[j], acc[0][j]);
                acc[1][j] = fmaf(a1, w[j], acc[1][j]);
            }
        }
    }

    #pragma unroll
    for (int j = 0; j < 8; ++j) {
        float b = be1[tx * 8 + j];
        #pragma unroll
        for (int i = 0; i < 2; ++i) {
            sH[ty * 2 + i][tx * 8 + j] = fmaxf(acc[i][j] + b, 0.f);
            acc[i][j] = 0.f;
        }
    }

    for (int kc = 0; kc < 4; ++kc) {
        __syncthreads();
        #pragma unroll
        for (int it = 0; it < 4; ++it) {
            int idx = it * 256 + tid;
            int r = idx >> 5, c4 = idx & 31;
            int p = (c4 >> 1) | ((c4 & 1) << 4);
            *(float4*)&sW[r][p * 4] = *(const float4*)&We2[(size_t)(kc * 32 + r) * 128 + c4 * 4];
        }
        __syncthreads();
        #pragma unroll
        for (int k = 0; k < 32; ++k) {
            float4 w0 = *(float4*)&sW[k][tx * 4];
            float4 w1 = *(float4*)&sW[k][64 + tx * 4];
            float w[8] = {w0.x, w0.y, w0.z, w0.w, w1.x, w1.y, w1.z, w1.w};
            float a0 = sH[ty * 2 + 0][kc * 32 + k];
            float a1 = sH[ty * 2 + 1][kc * 32 + k];
            #pragma unroll
            for (int j = 0; j < 8; ++j) {
                acc[0][j] = fmaf(a0, w[j], acc[0][j]);
                acc[1][j] = fmaf(a1, w[j], acc[1][j]);
            }
        }
    }

    __syncthreads();
    #pragma unroll
    for (int j = 0; j < 8; ++j) {
        float b = be2[tx * 8 + j];
        #pragma unroll
        for (int i = 0; i < 2; ++i)
            sH[ty * 2 + i][tx * 8 + j] = fmaxf(acc[i][j] + b, 0.f);
    }
    __syncthreads();

    const int c = tid & 127;
    const int h = tid >> 7;
    const int nR = sNRuns;
    for (int m = 0; m < nR; ++m) {
        int s = sRuns[m], epos = sRuns[m + 1];
        float part = 0.f;
        for (int r = s + h; r < epos; r += 2) part += sH[r][c];
        if (h) sRed[c] = part;
        __syncthreads();
        if (!h) {
            float v = part + sRed[c];
            int d = sDest[s];
            float* dst = agg + (size_t)d * 128 + c;
            bool atom = (m == 0 && sAtomF) || (m == nR - 1 && sAtomL);
            if (atom) unsafeAtomicAdd(dst, v);
            else      *dst = v;
        }
        __syncthreads();
    }
}

// ---------------------------------------------------------------------------
// Round-0 fallback: full atomic scatter (no workspace at all).
// ---------------------------------------------------------------------------
__global__ __launch_bounds__(256) void edge_kernel(
    const float* __restrict__ x, const int* __restrict__ eidx,
    const float* __restrict__ eattr,
    const float* __restrict__ We1, const float* __restrict__ be1,
    const float* __restrict__ We2, const float* __restrict__ be2,
    float* __restrict__ agg)
{
    __shared__ alignas(16) float sA[32][292];
    __shared__ alignas(16) float sW[32][128];
    __shared__ alignas(16) float sH[32][132];
    __shared__ int sDest[32];

    const int tid = threadIdx.x;
    const int tx = tid & 15;
    const int ty = tid >> 4;
    const int e0 = blockIdx.x * 32;

    if (tid < 32) sDest[tid] = clampi(eidx[N_EDGES + e0 + tid], N_NODES);

    #pragma unroll
    for (int it = 0; it < 9; ++it) {
        int idx = it * 256 + tid;
        int e = idx / 72;
        int c = idx - e * 72;
        const float* p;
        if (c < 32)      p = x + (size_t)clampi(eidx[e0 + e], N_NODES) * 128 + c * 4;
        else if (c < 64) p = x + (size_t)clampi(eidx[N_EDGES + e0 + e], N_NODES) * 128 + (c - 32) * 4;
        else             p = eattr + (size_t)(e0 + e) * 32 + (c - 64) * 4;
        *(float4*)&sA[e][c * 4] = *(const float4*)p;
    }

    float acc[2][8];
    #pragma unroll
    for (int i = 0; i < 2; ++i)
        #pragma unroll
        for (int j = 0; j < 8; ++j) acc[i][j] = 0.f;

    for (int kc = 0; kc < 9; ++kc) {
        __syncthreads();
        #pragma unroll
        for (int it = 0; it < 4; ++it) {
            int idx = it * 256 + tid;
            int r = idx >> 5, c4 = idx & 31;
            *(float4*)&sW[r][c4 * 4] = *(const float4*)&We1[(size_t)(kc * 32 + r) * 128 + c4 * 4];
        }
        __syncthreads();
        #pragma unroll
        for (int k = 0; k < 32; ++k) {
            float4 w0 = *(float4*)&sW[k][tx * 8];
            float4 w1 = *(float4*)&sW[k][tx * 8 + 4];
            float w[8] = {w0.x, w0.y, w0.z, w0.w, w1.x, w1.y, w1.z, w1.w};
            float a0 = sA[ty * 2 + 0][kc * 32 + k];
            float a1 = sA[ty * 2 + 1][kc * 32 + k];
            #pragma unroll
            for (int j = 0; j < 8; ++j) {
                acc[0][j] = fmaf(a0, w[j], acc[0][j]);
                acc[1][j] = fmaf(a1, w[j], acc[1][j]);
            }
        }
    }

    #pragma unroll
    for (int j = 0; j < 8; ++j) {
        float b = be1[tx * 8 + j];
        #pragma unroll
        for (int i = 0; i < 2; ++i) {
            sH[ty * 2 + i][tx * 8 + j] = fmaxf(acc[i][j] + b, 0.f);
            acc[i][j] = 0.f;
        }
    }

    for (int kc = 0; kc < 4; ++kc) {
        __syncthreads();
        #pragma unroll
        for (int it = 0; it < 4; ++it) {
            int idx = it * 256 + tid;
            int r = idx >> 5, c4 = idx & 31;
            *(float4*)&sW[r][c4 * 4] = *(const float4*)&We2[(size_t)(kc * 32 + r) * 128 + c4 * 4];
        }
        __syncthreads();
        #pragma unroll
        for (int k = 0; k < 32; ++k) {
            float4 w0 = *(float4*)&sW[k][tx * 8];
            float4 w1 = *(float4*)&sW[k][tx * 8 + 4];
            float w[8] = {w0.x, w0.y, w0.z, w0.w, w1.x, w1.y, w1.z, w1.w};
            float a0 = sH[ty * 2 + 0][kc * 32 + k];
            float a1 = sH[ty * 2 + 1][kc * 32 + k];
            #pragma unroll
            for (int j = 0; j < 8; ++j) {
                acc[0][j] = fmaf(a0, w[j], acc[0][j]);
                acc[1][j] = fmaf(a1, w[j], acc[1][j]);
            }
        }
    }

    #pragma unroll
    for (int i = 0; i < 2; ++i) {
        int d = sDest[ty * 2 + i];
        float* dst = agg + (size_t)d * 128 + tx * 8;
        #pragma unroll
        for (int j = 0; j < 8; ++j) {
            float b = be2[tx * 8 + j];
            float v = fmaxf(acc[i][j] + b, 0.f);
            unsafeAtomicAdd(dst + j, v);
        }
    }
}

// ---------------------------------------------------------------------------
// Fused node+global kernel (unchanged): one block (256 threads) per graph.
// ---------------------------------------------------------------------------
__global__ __launch_bounds__(256) void node_global_kernel(
    const float* __restrict__ x, const float* __restrict__ agg,
    const int* __restrict__ batch,
    const float* __restrict__ Wg, const float* __restrict__ bg,
    const float* __restrict__ Wn, const float* __restrict__ bn,
    const float* __restrict__ u, const float* __restrict__ Wu,
    const float* __restrict__ bu,
    float* __restrict__ xw_out, float* __restrict__ out)
{
    __shared__ alignas(16) float sA[32][260];
    __shared__ alignas(16) float sW[32][128];
    __shared__ alignas(16) float redu[16][132];
    __shared__ alignas(16) float cat[192];
    __shared__ int sRange[2];

    const int tid = threadIdx.x;
    const int tx = tid & 15;
    const int ty = tid >> 4;
    const int g = blockIdx.x;

    if (tid == 0) {
        int lo = 0, hi = N_NODES;
        while (lo < hi) { int m = (lo + hi) >> 1; if (batch[m] < g) lo = m + 1; else hi = m; }
        sRange[0] = lo;
        hi = N_NODES;
        while (lo < hi) { int m = (lo + hi) >> 1; if (batch[m] < g + 1) lo = m + 1; else hi = m; }
        sRange[1] = lo;
    }
    __syncthreads();
    const int start = sRange[0];
    const int end   = sRange[1];

    float pool_acc[8];
    #pragma unroll
    for (int j = 0; j < 8; ++j) pool_acc[j] = 0.f;

    for (int n0 = start; n0 < end; n0 += 32) {
        #pragma unroll
        for (int it = 0; it < 4; ++it) {
            int idx = it * 256 + tid;
            int r = idx >> 5, c = idx & 31;
            float4 v = make_float4(0.f, 0.f, 0.f, 0.f);
            if (n0 + r < end) v = *(const float4*)&x[(size_t)(n0 + r) * 128 + c * 4];
            *(float4*)&sA[r][c * 4] = v;
        }
        #pragma unroll
        for (int it = 0; it < 4; ++it) {
            int idx = it * 256 + tid;
            int r = idx >> 5, c = idx & 31;
            float4 v = make_float4(0.f, 0.f, 0.f, 0.f);
            if (n0 + r < end) v = *(const float4*)&agg[(size_t)(n0 + r) * 128 + c * 4];
            *(float4*)&sA[r][128 + c * 4] = v;
        }

        float acc[2][8];
        #pragma unroll
        for (int i = 0; i < 2; ++i)
            #pragma unroll
            for (int j = 0; j < 8; ++j) acc[i][j] = 0.f;

        for (int kc = 0; kc < 8; ++kc) {
            __syncthreads();
            #pragma unroll
            for (int it = 0; it < 4; ++it) {
                int idx = it * 256 + tid;
                int r = idx >> 5, c4 = idx & 31;
                *(float4*)&sW[r][c4 * 4] = *(const float4*)&Wg[(size_t)(kc * 32 + r) * 128 + c4 * 4];
            }
            __syncthreads();
            #pragma unroll
            for (int k = 0; k < 32; ++k) {
                float4 w0 = *(float4*)&sW[k][tx * 8];
                float4 w1 = *(float4*)&sW[k][tx * 8 + 4];
                float w[8] = {w0.x, w0.y, w0.z, w0.w, w1.x, w1.y, w1.z, w1.w};
                float a0 = sA[ty * 2 + 0][kc * 32 + k];
                float a1 = sA[ty * 2 + 1][kc * 32 + k];
                #pragma unroll
                for (int j = 0; j < 8; ++j) {
                    acc[0][j] = fmaf(a0, w[j], acc[0][j]);
                    acc[1][j] = fmaf(a1, w[j], acc[1][j]);
                }
            }
        }

        float gate[2][8];
        #pragma unroll
        for (int i = 0; i < 2; ++i) {
            int n = n0 + ty * 2 + i;
            #pragma unroll
            for (int j = 0; j < 8; ++j) {
                float v = acc[i][j] + bg[tx * 8 + j];
                gate[i][j] = 1.0f / (1.0f + __expf(-v));
                acc[i][j] = 0.f;
            }
            if (n < end) {
                float4 g0 = make_float4(gate[i][0], gate[i][1], gate[i][2], gate[i][3]);
                float4 g1 = make_float4(gate[i][4], gate[i][5], gate[i][6], gate[i][7]);
                *(float4*)&xw_out[(size_t)n * 128 + tx * 8]     = g0;
                *(float4*)&xw_out[(size_t)n * 128 + tx * 8 + 4] = g1;
            }
        }

        for (int kc = 0; kc < 8; ++kc) {
            __syncthreads();
            #pragma unroll
            for (int it = 0; it < 4; ++it) {
                int idx = it * 256 + tid;
                int r = idx >> 5, c4 = idx & 31;
                *(float4*)&sW[r][c4 * 4] = *(const float4*)&Wn[(size_t)(kc * 32 + r) * 128 + c4 * 4];
            }
            __syncthreads();
            #pragma unroll
            for (int k = 0; k < 32; ++k) {
                float4 w0 = *(float4*)&sW[k][tx * 8];
                float4 w1 = *(float4*)&sW[k][tx * 8 + 4];
                float w[8] = {w0.x, w0.y, w0.z, w0.w, w1.x, w1.y, w1.z, w1.w};
                float a0 = sA[ty * 2 + 0][kc * 32 + k];
                float a1 = sA[ty * 2 + 1][kc * 32 + k];
                #pragma unroll
                for (int j = 0; j < 8; ++j) {
                    acc[0][j] = fmaf(a0, w[j], acc[0][j]);
                    acc[1][j] = fmaf(a1, w[j], acc[1][j]);
                }
            }
        }

        #pragma unroll
        for (int i = 0; i < 2; ++i) {
            int n = n0 + ty * 2 + i;
            if (n < end) {
                #pragma unroll
                for (int j = 0; j < 8; ++j) {
                    float v = fmaxf(acc[i][j] + bn[tx * 8 + j], 0.f);
                    pool_acc[j] += gate[i][j] * v;
                }
            }
        }
        __syncthreads();
    }

    #pragma unroll
    for (int j = 0; j < 8; ++j) redu[ty][tx * 8 + j] = pool_acc[j];
    __syncthreads();
    #pragma unroll
    for (int s = 8; s >= 1; s >>= 1) {
        if (ty < s) {
            #pragma unroll
            for (int j = 0; j < 8; ++j)
                redu[ty][tx * 8 + j] += redu[ty + s][tx * 8 + j];
        }
        __syncthreads();
    }

    float cnt = fmaxf((float)(end - start), 1.0f);
    if (tid < 64)        cat[tid] = u[g * 64 + tid];
    else if (tid < 192)  cat[tid] = redu[0][tid - 64] / cnt;
    __syncthreads();
    if (tid < 64) {
        float acc = bu[tid];
        #pragma unroll 4
        for (int k = 0; k < 192; ++k)
            acc = fmaf(cat[k], Wu[k * 64 + tid], acc);
        out[g * 64 + tid] = fmaxf(acc, 0.f);
    }
}

// ---------------------------------------------------------------------------
extern "C" void kernel_launch(void* const* d_in, const int* in_sizes, int n_in,
                              void* d_out, int out_size, void* d_ws, size_t ws_size,
                              hipStream_t stream) {
    const float* x     = (const float*)d_in[0];
    const int*   eidx  = (const int*)d_in[1];
    const float* eattr = (const float*)d_in[2];
    const float* u     = (const float*)d_in[3];
    const int*   batch = (const int*)d_in[4];
    const float* We1   = (const float*)d_in[5];
    const float* be1   = (const float*)d_in[6];
    const float* We2   = (const float*)d_in[7];
    const float* be2   = (const float*)d_in[8];
    const float* Wg    = (const float*)d_in[9];
    const float* bg    = (const float*)d_in[10];
    const float* Wn    = (const float*)d_in[11];
    const float* bn    = (const float*)d_in[12];
    const float* Wu    = (const float*)d_in[13];
    const float* bu    = (const float*)d_in[14];

    float* out    = (float*)d_out;                 // chunk 0: u_new [512*64] fp32
    float* xw_out = out + N_GRAPHS * D_GLOB;       // chunk 1: x_weights [50000*128] fp32
    float* agg    = xw_out;                        // fp32 agg aliases chunk 1

    // zero the agg region (d_out is re-poisoned before every timed launch)
    hipMemsetAsync(xw_out, 0, (size_t)N_NODES * D_HID * sizeof(float), stream);

    const size_t sortWs = (size_t)(2 * N_NODES + N_EDGES) * sizeof(int);        // 3.6 MB
    const size_t fullWs = sortWs + (size_t)N_EDGES * D_HID * sizeof(float);     // +409.6 MB

    if (d_ws != nullptr && ws_size >= fullWs) {
        int* counts = (int*)d_ws;
        int* cursor = counts + N_NODES;
        int* perm   = cursor + N_NODES;
        float* h_ws = (float*)((char*)d_ws + sortWs);
        hipMemsetAsync(counts, 0, (size_t)N_NODES * sizeof(int), stream);
        hist_kernel<<<(N_EDGES + 255) / 256, 256, 0, stream>>>(eidx, counts);
        scan_kernel<<<1, 256, 0, stream>>>(counts, cursor);
        scatter_kernel<<<(N_EDGES + 255) / 256, 256, 0, stream>>>(eidx, cursor, perm);
        edge_l1_kernel<<<256, 256, 0, stream>>>(x, eidx, eattr, perm, We1, be1, h_ws);
        edge_l2_kernel<<<256, 256, 0, stream>>>(h_ws, eidx, perm, We2, be2, agg);
    } else if (d_ws != nullptr && ws_size >= sortWs) {
        int* counts = (int*)d_ws;
        int* cursor = counts + N_NODES;
        int* perm   = cursor + N_NODES;
        hipMemsetAsync(counts, 0, (size_t)N_NODES * sizeof(int), stream);
        hist_kernel<<<(N_EDGES + 255) / 256, 256, 0, stream>>>(eidx, counts);
        scan_kernel<<<1, 256, 0, stream>>>(counts, cursor);
        scatter_kernel<<<(N_EDGES + 255) / 256, 256, 0, stream>>>(eidx, cursor, perm);
        edge_kernel_sorted<<<N_EDGES / 32, 256, 0, stream>>>(x, eidx, eattr, perm,
                                                             We1, be1, We2, be2, agg);
    } else {
        edge_kernel<<<N_EDGES / 32, 256, 0, stream>>>(x, eidx, eattr, We1, be1, We2, be2, agg);
    }
    node_global_kernel<<<N_GRAPHS, 256, 0, stream>>>(x, agg, batch, Wg, bg, Wn, bn,
                                                     u, Wu, bu, xw_out, out);
}

// Round 3
// 1756.930 us; speedup vs baseline: 2.9277x; 1.8736x over previous
//
#include <hip/hip_runtime.h>

#define N_NODES 50000
#define N_EDGES 800000
#define N_GRAPHS 512
#define D_IN 128
#define D_EDGE 32
#define D_HID 128
#define D_GLOB 64
#define TILE 256
#define NT (N_EDGES / TILE)      // 3125 tiles, exact

// Static device scratch: allocated at module load (zero-init .bss), so the
// pipeline no longer depends on ws_size (round-2's 413MB ws requirement was
// never met -> fallback ran). 410 MB of 288 GB HBM.
__device__ float g_h[(size_t)N_EDGES * D_HID];
__device__ int g_counts[N_NODES];
__device__ int g_cursor[N_NODES];
__device__ int g_perm[N_EDGES];

__device__ __forceinline__ int clampi(int v, int hi) {   // [0, hi)
    return v < 0 ? 0 : (v >= hi ? hi - 1 : v);
}

// ---------------------------------------------------------------------------
// Counting-sort of edges by destination node.
// ---------------------------------------------------------------------------
__global__ void zero_counts_kernel()
{
    int i = blockIdx.x * 256 + threadIdx.x;
    if (i < N_NODES) g_counts[i] = 0;
}

__global__ void hist_kernel(const int* __restrict__ eidx)
{
    int e = blockIdx.x * 256 + threadIdx.x;
    if (e < N_EDGES) atomicAdd(&g_counts[clampi(eidx[N_EDGES + e], N_NODES)], 1);
}

__global__ __launch_bounds__(256) void scan_kernel()
{
    __shared__ int part[256];
    const int t = threadIdx.x;
    const int chunk = (N_NODES + 255) / 256;          // 196
    int lo = t * chunk;
    int hi = lo + chunk; if (hi > N_NODES) hi = N_NODES;
    int s = 0;
    for (int i = lo; i < hi; ++i) s += g_counts[i];
    part[t] = s;
    __syncthreads();
    if (t == 0) {
        int run = 0;
        for (int i = 0; i < 256; ++i) { int v = part[i]; part[i] = run; run += v; }
    }
    __syncthreads();
    int run = part[t];
    for (int i = lo; i < hi; ++i) { g_cursor[i] = run; run += g_counts[i]; }
}

__global__ void scatter_kernel(const int* __restrict__ eidx)
{
    int e = blockIdx.x * 256 + threadIdx.x;
    if (e < N_EDGES) {
        int d = clampi(eidx[N_EDGES + e], N_NODES);
        int p = atomicAdd(&g_cursor[d], 1);
        g_perm[p] = e;
    }
}

// ---------------------------------------------------------------------------
// Register-tile GEMM core: 512 threads, tx = tid&15 owns cols {q*64+tx*4+j},
// ty = tid>>4 owns 8 rows. A operand streams straight from global into
// double-buffered registers (no LDS); W is LDS-resident, read 2xb128 per k.
// The 16-tx pattern is a 4-way lane broadcast over 16 granules spanning all
// 32 banks -> conflict-free, ~2cyc per read. LDS:VALU ~ 80:1024 per k-group.
// ---------------------------------------------------------------------------
template<int KBASE>
__device__ __forceinline__ void step4(const float* __restrict__ sW, int kg, int tx,
                                      const float4 (&a)[8], float (&acc)[8][8])
{
    #pragma unroll
    for (int kk = 0; kk < 4; ++kk) {
        const float* wr = sW + (size_t)(KBASE + kg * 4 + kk) * 128 + tx * 4;
        float4 w0 = *(const float4*)(wr);
        float4 w1 = *(const float4*)(wr + 64);
        #pragma unroll
        for (int r = 0; r < 8; ++r) {
            const float av = ((const float*)&a[r])[kk];
            acc[r][0] = fmaf(av, w0.x, acc[r][0]);
            acc[r][1] = fmaf(av, w0.y, acc[r][1]);
            acc[r][2] = fmaf(av, w0.z, acc[r][2]);
            acc[r][3] = fmaf(av, w0.w, acc[r][3]);
            acc[r][4] = fmaf(av, w1.x, acc[r][4]);
            acc[r][5] = fmaf(av, w1.y, acc[r][5]);
            acc[r][6] = fmaf(av, w1.z, acc[r][6]);
            acc[r][7] = fmaf(av, w1.w, acc[r][7]);
        }
    }
}

template<int KBASE, int KG>
__device__ __forceinline__ void gemm_seg(const float* __restrict__ sW, int tx,
                                         const float* const (&bp)[8],
                                         float (&acc)[8][8])
{
    float4 a0[8], a1[8];
    #pragma unroll
    for (int r = 0; r < 8; ++r) a0[r] = *(const float4*)(bp[r]);
    #pragma unroll 1
    for (int kg = 0; kg < KG; kg += 2) {
        #pragma unroll
        for (int r = 0; r < 8; ++r) a1[r] = *(const float4*)(bp[r] + (kg + 1) * 4);
        step4<KBASE>(sW, kg, tx, a0, acc);
        if (kg + 2 < KG) {
            #pragma unroll
            for (int r = 0; r < 8; ++r) a0[r] = *(const float4*)(bp[r] + (kg + 2) * 4);
        }
        step4<KBASE>(sW, kg + 1, tx, a1, acc);
    }
}

// ---------------------------------------------------------------------------
// Edge layer-1: We1 (288x128 = 147 KB) LDS-resident for the whole persistent
// block. 512 threads (2 waves/SIMD), 256-edge tiles. Gather A rows direct to
// registers, GEMM K=288 with zero k-loop barriers, write h to g_h.
// ---------------------------------------------------------------------------
__global__ __launch_bounds__(512, 2) void edge_l1_kernel(
    const float* __restrict__ x, const int* __restrict__ eidx,
    const float* __restrict__ eattr,
    const float* __restrict__ We1, const float* __restrict__ be1)
{
    __shared__ float sW[288 * 128];          // 147456 B
    __shared__ int sSrc[256], sDst[256], sEdg[256];

    const int tid = threadIdx.x;
    const int tx = tid & 15;
    const int ty = tid >> 4;

    #pragma unroll 4
    for (int it = 0; it < 72; ++it)
        ((float4*)sW)[it * 512 + tid] = ((const float4*)We1)[it * 512 + tid];

    const float4 b0 = *(const float4*)&be1[ 0 + tx * 4];
    const float4 b1 = *(const float4*)&be1[64 + tx * 4];

    for (int t = blockIdx.x; t < NT; t += gridDim.x) {
        const int e0 = t * TILE;
        __syncthreads();                     // sW ready / prior tile done
        if (tid < 256) {
            int p = g_perm[e0 + tid];
            sEdg[tid] = p;
            sSrc[tid] = clampi(eidx[p], N_NODES);
            sDst[tid] = clampi(eidx[N_EDGES + p], N_NODES);
        }
        __syncthreads();

        float acc[8][8];
        #pragma unroll
        for (int r = 0; r < 8; ++r)
            #pragma unroll
            for (int c = 0; c < 8; ++c) acc[r][c] = 0.f;

        {
            const float* bp[8];
            #pragma unroll
            for (int r = 0; r < 8; ++r) bp[r] = x + (size_t)sSrc[ty * 8 + r] * 128;
            gemm_seg<0, 32>(sW, tx, bp, acc);
        }
        {
            const float* bp[8];
            #pragma unroll
            for (int r = 0; r < 8; ++r) bp[r] = x + (size_t)sDst[ty * 8 + r] * 128;
            gemm_seg<128, 32>(sW, tx, bp, acc);
        }
        {
            const float* bp[8];
            #pragma unroll
            for (int r = 0; r < 8; ++r) bp[r] = eattr + (size_t)sEdg[ty * 8 + r] * 32;
            gemm_seg<256, 8>(sW, tx, bp, acc);
        }

        #pragma unroll
        for (int r = 0; r < 8; ++r) {
            float* dst = g_h + (size_t)(e0 + ty * 8 + r) * 128 + tx * 4;
            float4 v;
            v.x = fmaxf(acc[r][0] + b0.x, 0.f); v.y = fmaxf(acc[r][1] + b0.y, 0.f);
            v.z = fmaxf(acc[r][2] + b0.z, 0.f); v.w = fmaxf(acc[r][3] + b0.w, 0.f);
            *(float4*)(dst) = v;
            v.x = fmaxf(acc[r][4] + b1.x, 0.f); v.y = fmaxf(acc[r][5] + b1.y, 0.f);
            v.z = fmaxf(acc[r][6] + b1.z, 0.f); v.w = fmaxf(acc[r][7] + b1.w, 0.f);
            *(float4*)(dst + 64) = v;
        }
    }
}

// ---------------------------------------------------------------------------
// Edge layer-2 + scatter: We2 (64 KB) + 128-row staging (67.6 KB) LDS-resident,
// 512 threads. GEMM K=128 on contiguous h rows; per 128-row subtile stage msg
// in LDS (floor-optimal bank pattern) and segment-reduce per dest run, one
// wave per run. Atomics only where a run crosses a subtile/tile boundary.
// ---------------------------------------------------------------------------
__global__ __launch_bounds__(512, 2) void edge_l2_kernel(
    const int* __restrict__ eidx,
    const float* __restrict__ We2, const float* __restrict__ be2,
    float* __restrict__ agg)
{
    __shared__ float sW[128 * 128];          // 65536 B
    __shared__ float sRed[128][132];         // 67584 B
    __shared__ int sDest[256];
    __shared__ int sRunS[2][130];
    __shared__ int sNR[2], sAF[2], sAL[2];

    const int tid = threadIdx.x;
    const int tx = tid & 15;
    const int ty = tid >> 4;
    const int wid = tid >> 6;
    const int lane = tid & 63;

    #pragma unroll 4
    for (int it = 0; it < 8; ++it)
        ((float4*)sW)[it * 512 + tid] = ((const float4*)We2)[it * 512 + tid];

    const float4 c0 = *(const float4*)&be2[ 0 + tx * 4];
    const float4 c1 = *(const float4*)&be2[64 + tx * 4];

    for (int t = blockIdx.x; t < NT; t += gridDim.x) {
        const int e0 = t * TILE;
        __syncthreads();                     // sW ready / prior tile done
        if (tid < 256)
            sDest[tid] = clampi(eidx[N_EDGES + g_perm[e0 + tid]], N_NODES);
        __syncthreads();

        if (tid < 2) {                       // run detection, one lane per subtile
            const int base = tid * 128;
            int prev;
            if (base == 0)
                prev = (e0 > 0) ? clampi(eidx[N_EDGES + g_perm[e0 - 1]], N_NODES) : -1;
            else
                prev = sDest[base - 1];
            sAF[tid] = (prev == sDest[base]) ? 1 : 0;
            int n = 0;
            for (int i = 0; i < 128; ++i) {
                int d = sDest[base + i];
                if (i == 0 || d != sDest[base + i - 1]) sRunS[tid][n++] = base + i;
            }
            sRunS[tid][n] = base + 128;
            sNR[tid] = n;
            int nxt;
            if (base + 128 == 256)
                nxt = (e0 + 256 < N_EDGES) ? clampi(eidx[N_EDGES + g_perm[e0 + 256]], N_NODES) : -1;
            else
                nxt = sDest[128];
            sAL[tid] = (nxt == sDest[base + 127]) ? 1 : 0;
        }

        float acc[8][8];
        #pragma unroll
        for (int r = 0; r < 8; ++r)
            #pragma unroll
            for (int c = 0; c < 8; ++c) acc[r][c] = 0.f;

        {
            const float* bp[8];
            #pragma unroll
            for (int r = 0; r < 8; ++r) bp[r] = g_h + (size_t)(e0 + ty * 8 + r) * 128;
            gemm_seg<0, 32>(sW, tx, bp, acc);
        }

        #pragma unroll 1
        for (int g2 = 0; g2 < 2; ++g2) {
            __syncthreads();                 // prior subtile reads done / runs ready
            if ((ty >> 4) == g2) {           // 16 ty groups own this 128-row subtile
                const int lr = (ty & 15) * 8;
                #pragma unroll
                for (int r = 0; r < 8; ++r) {
                    float4 v;
                    v.x = fmaxf(acc[r][0] + c0.x, 0.f); v.y = fmaxf(acc[r][1] + c0.y, 0.f);
                    v.z = fmaxf(acc[r][2] + c0.z, 0.f); v.w = fmaxf(acc[r][3] + c0.w, 0.f);
                    *(float4*)&sRed[lr + r][ 0 + tx * 4] = v;
                    v.x = fmaxf(acc[r][4] + c1.x, 0.f); v.y = fmaxf(acc[r][5] + c1.y, 0.f);
                    v.z = fmaxf(acc[r][6] + c1.z, 0.f); v.w = fmaxf(acc[r][7] + c1.w, 0.f);
                    *(float4*)&sRed[lr + r][64 + tx * 4] = v;
                }
            }
            __syncthreads();
            const int nR = sNR[g2];
            for (int m = wid; m < nR; m += 8) {   // one wave per run
                const int s = sRunS[g2][m]     - g2 * 128;
                const int e = sRunS[g2][m + 1] - g2 * 128;
                float v0 = 0.f, v1 = 0.f;
                for (int r = s; r < e; ++r) { v0 += sRed[r][lane]; v1 += sRed[r][lane + 64]; }
                const int d = sDest[g2 * 128 + s];
                float* dst = agg + (size_t)d * 128;
                const bool atom = (m == 0 && sAF[g2]) || (m == nR - 1 && sAL[g2]);
                if (atom) {
                    unsafeAtomicAdd(dst + lane,      v0);
                    unsafeAtomicAdd(dst + lane + 64, v1);
                } else {
                    dst[lane]      = v0;         // exclusive owner of this dest
                    dst[lane + 64] = v1;
                }
            }
        }
    }
}

// ---------------------------------------------------------------------------
// Fused node+global kernel (unchanged): one block (256 threads) per graph.
// ---------------------------------------------------------------------------
__global__ __launch_bounds__(256) void node_global_kernel(
    const float* __restrict__ x, const float* __restrict__ agg,
    const int* __restrict__ batch,
    const float* __restrict__ Wg, const float* __restrict__ bg,
    const float* __restrict__ Wn, const float* __restrict__ bn,
    const float* __restrict__ u, const float* __restrict__ Wu,
    const float* __restrict__ bu,
    float* __restrict__ xw_out, float* __restrict__ out)
{
    __shared__ alignas(16) float sA[32][260];
    __shared__ alignas(16) float sW[32][128];
    __shared__ alignas(16) float redu[16][132];
    __shared__ alignas(16) float cat[192];
    __shared__ int sRange[2];

    const int tid = threadIdx.x;
    const int tx = tid & 15;
    const int ty = tid >> 4;
    const int g = blockIdx.x;

    if (tid == 0) {
        int lo = 0, hi = N_NODES;
        while (lo < hi) { int m = (lo + hi) >> 1; if (batch[m] < g) lo = m + 1; else hi = m; }
        sRange[0] = lo;
        hi = N_NODES;
        while (lo < hi) { int m = (lo + hi) >> 1; if (batch[m] < g + 1) lo = m + 1; else hi = m; }
        sRange[1] = lo;
    }
    __syncthreads();
    const int start = sRange[0];
    const int end   = sRange[1];

    float pool_acc[8];
    #pragma unroll
    for (int j = 0; j < 8; ++j) pool_acc[j] = 0.f;

    for (int n0 = start; n0 < end; n0 += 32) {
        #pragma unroll
        for (int it = 0; it < 4; ++it) {
            int idx = it * 256 + tid;
            int r = idx >> 5, c = idx & 31;
            float4 v = make_float4(0.f, 0.f, 0.f, 0.f);
            if (n0 + r < end) v = *(const float4*)&x[(size_t)(n0 + r) * 128 + c * 4];
            *(float4*)&sA[r][c * 4] = v;
        }
        #pragma unroll
        for (int it = 0; it < 4; ++it) {
            int idx = it * 256 + tid;
            int r = idx >> 5, c = idx & 31;
            float4 v = make_float4(0.f, 0.f, 0.f, 0.f);
            if (n0 + r < end) v = *(const float4*)&agg[(size_t)(n0 + r) * 128 + c * 4];
            *(float4*)&sA[r][128 + c * 4] = v;
        }

        float acc[2][8];
        #pragma unroll
        for (int i = 0; i < 2; ++i)
            #pragma unroll
            for (int j = 0; j < 8; ++j) acc[i][j] = 0.f;

        for (int kc = 0; kc < 8; ++kc) {
            __syncthreads();
            #pragma unroll
            for (int it = 0; it < 4; ++it) {
                int idx = it * 256 + tid;
                int r = idx >> 5, c4 = idx & 31;
                *(float4*)&sW[r][c4 * 4] = *(const float4*)&Wg[(size_t)(kc * 32 + r) * 128 + c4 * 4];
            }
            __syncthreads();
            #pragma unroll
            for (int k = 0; k < 32; ++k) {
                float4 w0 = *(float4*)&sW[k][tx * 8];
                float4 w1 = *(float4*)&sW[k][tx * 8 + 4];
                float w[8] = {w0.x, w0.y, w0.z, w0.w, w1.x, w1.y, w1.z, w1.w};
                float a0 = sA[ty * 2 + 0][kc * 32 + k];
                float a1 = sA[ty * 2 + 1][kc * 32 + k];
                #pragma unroll
                for (int j = 0; j < 8; ++j) {
                    acc[0][j] = fmaf(a0, w[j], acc[0][j]);
                    acc[1][j] = fmaf(a1, w[j], acc[1][j]);
                }
            }
        }

        float gate[2][8];
        #pragma unroll
        for (int i = 0; i < 2; ++i) {
            int n = n0 + ty * 2 + i;
            #pragma unroll
            for (int j = 0; j < 8; ++j) {
                float v = acc[i][j] + bg[tx * 8 + j];
                gate[i][j] = 1.0f / (1.0f + __expf(-v));
                acc[i][j] = 0.f;
            }
            if (n < end) {
                float4 g0 = make_float4(gate[i][0], gate[i][1], gate[i][2], gate[i][3]);
                float4 g1 = make_float4(gate[i][4], gate[i][5], gate[i][6], gate[i][7]);
                *(float4*)&xw_out[(size_t)n * 128 + tx * 8]     = g0;
                *(float4*)&xw_out[(size_t)n * 128 + tx * 8 + 4] = g1;
            }
        }

        for (int kc = 0; kc < 8; ++kc) {
            __syncthreads();
            #pragma unroll
            for (int it = 0; it < 4; ++it) {
                int idx = it * 256 + tid;
                int r = idx >> 5, c4 = idx & 31;
                *(float4*)&sW[r][c4 * 4] = *(const float4*)&Wn[(size_t)(kc * 32 + r) * 128 + c4 * 4];
            }
            __syncthreads();
            #pragma unroll
            for (int k = 0; k < 32; ++k) {
                float4 w0 = *(float4*)&sW[k][tx * 8];
                float4 w1 = *(float4*)&sW[k][tx * 8 + 4];
                float w[8] = {w0.x, w0.y, w0.z, w0.w, w1.x, w1.y, w1.z, w1.w};
                float a0 = sA[ty * 2 + 0][kc * 32 + k];
                float a1 = sA[ty * 2 + 1][kc * 32 + k];
                #pragma unroll
                for (int j = 0; j < 8; ++j) {
                    acc[0][j] = fmaf(a0, w[j], acc[0][j]);
                    acc[1][j] = fmaf(a1, w[j], acc[1][j]);
                }
            }
        }

        #pragma unroll
        for (int i = 0; i < 2; ++i) {
            int n = n0 + ty * 2 + i;
            if (n < end) {
                #pragma unroll
                for (int j = 0; j < 8; ++j) {
                    float v = fmaxf(acc[i][j] + bn[tx * 8 + j], 0.f);
                    pool_acc[j] += gate[i][j] * v;
                }
            }
        }
        __syncthreads();
    }

    #pragma unroll
    for (int j = 0; j < 8; ++j) redu[ty][tx * 8 + j] = pool_acc[j];
    __syncthreads();
    #pragma unroll
    for (int s = 8; s >= 1; s >>= 1) {
        if (ty < s) {
            #pragma unroll
            for (int j = 0; j < 8; ++j)
                redu[ty][tx * 8 + j] += redu[ty + s][tx * 8 + j];
        }
        __syncthreads();
    }

    float cnt = fmaxf((float)(end - start), 1.0f);
    if (tid < 64)        cat[tid] = u[g * 64 + tid];
    else if (tid < 192)  cat[tid] = redu[0][tid - 64] / cnt;
    __syncthreads();
    if (tid < 64) {
        float acc = bu[tid];
        #pragma unroll 4
        for (int k = 0; k < 192; ++k)
            acc = fmaf(cat[k], Wu[k * 64 + tid], acc);
        out[g * 64 + tid] = fmaxf(acc, 0.f);
    }
}

// ---------------------------------------------------------------------------
extern "C" void kernel_launch(void* const* d_in, const int* in_sizes, int n_in,
                              void* d_out, int out_size, void* d_ws, size_t ws_size,
                              hipStream_t stream) {
    const float* x     = (const float*)d_in[0];
    const int*   eidx  = (const int*)d_in[1];
    const float* eattr = (const float*)d_in[2];
    const float* u     = (const float*)d_in[3];
    const int*   batch = (const int*)d_in[4];
    const float* We1   = (const float*)d_in[5];
    const float* be1   = (const float*)d_in[6];
    const float* We2   = (const float*)d_in[7];
    const float* be2   = (const float*)d_in[8];
    const float* Wg    = (const float*)d_in[9];
    const float* bg    = (const float*)d_in[10];
    const float* Wn    = (const float*)d_in[11];
    const float* bn    = (const float*)d_in[12];
    const float* Wu    = (const float*)d_in[13];
    const float* bu    = (const float*)d_in[14];

    float* out    = (float*)d_out;                 // chunk 0: u_new [512*64] fp32
    float* xw_out = out + N_GRAPHS * D_GLOB;       // chunk 1: x_weights [50000*128] fp32
    float* agg    = xw_out;                        // fp32 agg aliases chunk 1

    // zero the agg region (d_out is re-poisoned before every timed launch)
    hipMemsetAsync(xw_out, 0, (size_t)N_NODES * D_HID * sizeof(float), stream);

    zero_counts_kernel<<<(N_NODES + 255) / 256, 256, 0, stream>>>();
    hist_kernel<<<(N_EDGES + 255) / 256, 256, 0, stream>>>(eidx);
    scan_kernel<<<1, 256, 0, stream>>>();
    scatter_kernel<<<(N_EDGES + 255) / 256, 256, 0, stream>>>(eidx);
    edge_l1_kernel<<<256, 512, 0, stream>>>(x, eidx, eattr, We1, be1);
    edge_l2_kernel<<<256, 512, 0, stream>>>(eidx, We2, be2, agg);
    node_global_kernel<<<N_GRAPHS, 256, 0, stream>>>(x, agg, batch, Wg, bg, Wn, bn,
                                                     u, Wu, bu, xw_out, out);
}

// Round 4
// 1402.377 us; speedup vs baseline: 3.6679x; 1.2528x over previous
//
#include <hip/hip_runtime.h>

#define N_NODES 50000
#define N_EDGES 800000
#define N_GRAPHS 512
#define D_IN 128
#define D_EDGE 32
#define D_HID 128
#define D_GLOB 64
#define TILE 256
#define NT (N_EDGES / TILE)       // 3125 l2 tiles
#define NTE (N_EDGES / 128)       // 6250 edge_h tiles
#define NTP ((N_NODES + 127) / 128)  // 391 node_pre tiles

// Static device scratch (zero-init .bss at module load; no ws_size dependence).
__device__ float g_h[(size_t)N_EDGES * D_HID];        // 410 MB
__device__ float g_xab[(size_t)N_NODES * 256];        // 51.2 MB: [xa | xb] per node
__device__ int g_counts[N_NODES];
__device__ int g_cursor[N_NODES];
__device__ int g_perm[N_EDGES];

__device__ __forceinline__ int clampi(int v, int hi) {   // [0, hi)
    return v < 0 ? 0 : (v >= hi ? hi - 1 : v);
}

// ---------------------------------------------------------------------------
// Counting-sort of edges by destination node.
// ---------------------------------------------------------------------------
__global__ void zero_counts_kernel()
{
    int i = blockIdx.x * 256 + threadIdx.x;
    if (i < N_NODES) g_counts[i] = 0;
}

__global__ void hist_kernel(const int* __restrict__ eidx)
{
    int e = blockIdx.x * 256 + threadIdx.x;
    if (e < N_EDGES) atomicAdd(&g_counts[clampi(eidx[N_EDGES + e], N_NODES)], 1);
}

__global__ __launch_bounds__(256) void scan_kernel()
{
    __shared__ int part[256];
    const int t = threadIdx.x;
    const int chunk = (N_NODES + 255) / 256;          // 196
    int lo = t * chunk;
    int hi = lo + chunk; if (hi > N_NODES) hi = N_NODES;
    int s = 0;
    for (int i = lo; i < hi; ++i) s += g_counts[i];
    part[t] = s;
    __syncthreads();
    if (t == 0) {
        int run = 0;
        for (int i = 0; i < 256; ++i) { int v = part[i]; part[i] = run; run += v; }
    }
    __syncthreads();
    int run = part[t];
    for (int i = lo; i < hi; ++i) { g_cursor[i] = run; run += g_counts[i]; }
}

__global__ void scatter_kernel(const int* __restrict__ eidx)
{
    int e = blockIdx.x * 256 + threadIdx.x;
    if (e < N_EDGES) {
        int d = clampi(eidx[N_EDGES + e], N_NODES);
        int p = atomicAdd(&g_cursor[d], 1);
        g_perm[p] = e;
    }
}

// ---------------------------------------------------------------------------
// Register-tile GEMM core (8 rows x 8 cols per thread). A streams from global
// into double-buffered registers; W is LDS-resident with leading dim LD and
// second-column-group offset OFF. Conflict-free b128 reads (contiguous
// granules across tx lanes).
// ---------------------------------------------------------------------------
template<int KBASE, int LD, int OFF>
__device__ __forceinline__ void step4(const float* __restrict__ sW, int kg, int tx,
                                      const float4 (&a)[8], float (&acc)[8][8])
{
    #pragma unroll
    for (int kk = 0; kk < 4; ++kk) {
        const float* wr = sW + (size_t)(KBASE + kg * 4 + kk) * LD + tx * 4;
        float4 w0 = *(const float4*)(wr);
        float4 w1 = *(const float4*)(wr + OFF);
        #pragma unroll
        for (int r = 0; r < 8; ++r) {
            const float av = ((const float*)&a[r])[kk];
            acc[r][0] = fmaf(av, w0.x, acc[r][0]);
            acc[r][1] = fmaf(av, w0.y, acc[r][1]);
            acc[r][2] = fmaf(av, w0.z, acc[r][2]);
            acc[r][3] = fmaf(av, w0.w, acc[r][3]);
            acc[r][4] = fmaf(av, w1.x, acc[r][4]);
            acc[r][5] = fmaf(av, w1.y, acc[r][5]);
            acc[r][6] = fmaf(av, w1.z, acc[r][6]);
            acc[r][7] = fmaf(av, w1.w, acc[r][7]);
        }
    }
}

template<int KBASE, int KG, int LD, int OFF>
__device__ __forceinline__ void gemm_seg(const float* __restrict__ sW, int tx,
                                         const float* const (&bp)[8],
                                         float (&acc)[8][8])
{
    float4 a0[8], a1[8];
    #pragma unroll
    for (int r = 0; r < 8; ++r) a0[r] = *(const float4*)(bp[r]);
    #pragma unroll 1
    for (int kg = 0; kg < KG; kg += 2) {
        #pragma unroll
        for (int r = 0; r < 8; ++r) a1[r] = *(const float4*)(bp[r] + (kg + 1) * 4);
        step4<KBASE, LD, OFF>(sW, kg, tx, a0, acc);
        if (kg + 2 < KG) {
            #pragma unroll
            for (int r = 0; r < 8; ++r) a0[r] = *(const float4*)(bp[r] + (kg + 2) * 4);
        }
        step4<KBASE, LD, OFF>(sW, kg + 1, tx, a1, acc);
    }
}

// ---------------------------------------------------------------------------
// Node precompute: xab[n] = x[n] @ [We1_top | We1_bot]  (50000 x 128 x 256).
// Packed weight W'[k][c] = c<128 ? We1[k][c] : We1[128+k][c-128], 131 KB
// LDS-resident. 512 threads; tx in [0,32) owns cols {tx*4, 128+tx*4};
// ty in [0,16) owns 8 rows. No bias/relu here (applied in edge_h).
// ---------------------------------------------------------------------------
__global__ __launch_bounds__(512, 2) void node_pre_kernel(
    const float* __restrict__ x, const float* __restrict__ We1)
{
    __shared__ float sWp[128 * 256];     // 131072 B
    const int tid = threadIdx.x;
    const int tx = tid & 31;
    const int ty = tid >> 5;

    #pragma unroll 4
    for (int it = 0; it < 16; ++it) {
        int idx = it * 512 + tid;        // float4 index, 8192 total
        int k = idx >> 6;                // 64 float4 per 256-float row
        int c = (idx & 63) * 4;
        const float* src = (c < 128) ? (We1 + (size_t)k * 128 + c)
                                     : (We1 + (size_t)(128 + k) * 128 + (c - 128));
        *(float4*)&sWp[(size_t)idx * 4] = *(const float4*)src;
    }
    __syncthreads();

    for (int t = blockIdx.x; t < NTP; t += gridDim.x) {
        const int n0 = t * 128;
        float acc[8][8];
        #pragma unroll
        for (int r = 0; r < 8; ++r)
            #pragma unroll
            for (int c = 0; c < 8; ++c) acc[r][c] = 0.f;

        const float* bp[8];
        #pragma unroll
        for (int r = 0; r < 8; ++r) {
            int n = n0 + ty * 8 + r;
            if (n >= N_NODES) n = N_NODES - 1;           // tail: duplicate compute
            bp[r] = x + (size_t)n * 128;
        }
        gemm_seg<0, 32, 256, 128>(sWp, tx, bp, acc);

        #pragma unroll
        for (int r = 0; r < 8; ++r) {
            int n = n0 + ty * 8 + r;
            if (n < N_NODES) {
                float* dst = g_xab + (size_t)n * 256;
                *(float4*)(dst + tx * 4)       = make_float4(acc[r][0], acc[r][1], acc[r][2], acc[r][3]);
                *(float4*)(dst + 128 + tx * 4) = make_float4(acc[r][4], acc[r][5], acc[r][6], acc[r][7]);
            }
        }
    }
}

// ---------------------------------------------------------------------------
// Edge h kernel: h[i] = relu(xa[src] + xb[dst] + attr @ W1c + be1) for sorted
// edge i = perm-order. Only 16 KB LDS (W1c) -> 4 blocks/CU for gather-latency
// hiding. 256 threads; tx in [0,16) owns cols {tx*4, 64+tx*4}; ty in [0,16)
// owns 8 rows of the 128-edge tile.
// ---------------------------------------------------------------------------
__global__ __launch_bounds__(256, 4) void edge_h_kernel(
    const int* __restrict__ eidx, const float* __restrict__ eattr,
    const float* __restrict__ We1, const float* __restrict__ be1)
{
    __shared__ float sWc[32 * 128];      // 16384 B: We1 rows 256..288
    __shared__ int sSrc[128], sDst[128], sEdg[128];

    const int tid = threadIdx.x;
    const int tx = tid & 15;
    const int ty = tid >> 4;

    #pragma unroll
    for (int it = 0; it < 4; ++it) {
        int idx = it * 256 + tid;        // 1024 float4 total
        ((float4*)sWc)[idx] = ((const float4*)(We1 + (size_t)256 * 128))[idx];
    }

    const float4 b0 = *(const float4*)&be1[tx * 4];
    const float4 b1 = *(const float4*)&be1[64 + tx * 4];

    for (int t = blockIdx.x; t < NTE; t += gridDim.x) {
        const int e0 = t * 128;
        __syncthreads();                 // prior tile idx reads done / sWc ready
        if (tid < 128) {
            int p = g_perm[e0 + tid];
            sEdg[tid] = p;
            sSrc[tid] = clampi(eidx[p], N_NODES);
            sDst[tid] = clampi(eidx[N_EDGES + p], N_NODES);
        }
        __syncthreads();

        float acc[8][8];
        // init acc = xa[src] + xb[dst], 2 rows per batch (reg pressure)
        #pragma unroll
        for (int rp = 0; rp < 4; ++rp) {
            float4 xa0[2], xa1[2], xb0[2], xb1[2];
            #pragma unroll
            for (int i = 0; i < 2; ++i) {
                int row = ty * 8 + rp * 2 + i;
                const float* pa = g_xab + (size_t)sSrc[row] * 256;
                const float* pb = g_xab + (size_t)sDst[row] * 256 + 128;
                xa0[i] = *(const float4*)(pa + tx * 4);
                xa1[i] = *(const float4*)(pa + 64 + tx * 4);
                xb0[i] = *(const float4*)(pb + tx * 4);
                xb1[i] = *(const float4*)(pb + 64 + tx * 4);
            }
            #pragma unroll
            for (int i = 0; i < 2; ++i) {
                int r = rp * 2 + i;
                acc[r][0] = xa0[i].x + xb0[i].x; acc[r][1] = xa0[i].y + xb0[i].y;
                acc[r][2] = xa0[i].z + xb0[i].z; acc[r][3] = xa0[i].w + xb0[i].w;
                acc[r][4] = xa1[i].x + xb1[i].x; acc[r][5] = xa1[i].y + xb1[i].y;
                acc[r][6] = xa1[i].z + xb1[i].z; acc[r][7] = xa1[i].w + xb1[i].w;
            }
        }

        // attr GEMM: K = 32
        #pragma unroll 1
        for (int kg = 0; kg < 8; ++kg) {
            float4 av[8];
            #pragma unroll
            for (int r = 0; r < 8; ++r)
                av[r] = *(const float4*)(eattr + (size_t)sEdg[ty * 8 + r] * 32 + kg * 4);
            #pragma unroll
            for (int kk = 0; kk < 4; ++kk) {
                const float* wr = sWc + (size_t)(kg * 4 + kk) * 128 + tx * 4;
                float4 w0 = *(const float4*)(wr);
                float4 w1 = *(const float4*)(wr + 64);
                #pragma unroll
                for (int r = 0; r < 8; ++r) {
                    const float a = ((const float*)&av[r])[kk];
                    acc[r][0] = fmaf(a, w0.x, acc[r][0]);
                    acc[r][1] = fmaf(a, w0.y, acc[r][1]);
                    acc[r][2] = fmaf(a, w0.z, acc[r][2]);
                    acc[r][3] = fmaf(a, w0.w, acc[r][3]);
                    acc[r][4] = fmaf(a, w1.x, acc[r][4]);
                    acc[r][5] = fmaf(a, w1.y, acc[r][5]);
                    acc[r][6] = fmaf(a, w1.z, acc[r][6]);
                    acc[r][7] = fmaf(a, w1.w, acc[r][7]);
                }
            }
        }

        // bias + relu -> g_h (sorted order)
        #pragma unroll
        for (int r = 0; r < 8; ++r) {
            float* dst = g_h + (size_t)(e0 + ty * 8 + r) * 128 + tx * 4;
            float4 v;
            v.x = fmaxf(acc[r][0] + b0.x, 0.f); v.y = fmaxf(acc[r][1] + b0.y, 0.f);
            v.z = fmaxf(acc[r][2] + b0.z, 0.f); v.w = fmaxf(acc[r][3] + b0.w, 0.f);
            *(float4*)(dst) = v;
            v.x = fmaxf(acc[r][4] + b1.x, 0.f); v.y = fmaxf(acc[r][5] + b1.y, 0.f);
            v.z = fmaxf(acc[r][6] + b1.z, 0.f); v.w = fmaxf(acc[r][7] + b1.w, 0.f);
            *(float4*)(dst + 64) = v;
        }
    }
}

// ---------------------------------------------------------------------------
// Edge layer-2 + scatter (unchanged from round 3): We2 (64 KB) + 128-row
// staging LDS-resident, 512 threads. GEMM K=128 on contiguous h rows; per
// 128-row subtile stage msg in LDS and segment-reduce per dest run. Atomics
// only where a run crosses a subtile/tile boundary.
// ---------------------------------------------------------------------------
__global__ __launch_bounds__(512, 2) void edge_l2_kernel(
    const int* __restrict__ eidx,
    const float* __restrict__ We2, const float* __restrict__ be2,
    float* __restrict__ agg)
{
    __shared__ float sW[128 * 128];          // 65536 B
    __shared__ float sRed[128][132];         // 67584 B
    __shared__ int sDest[256];
    __shared__ int sRunS[2][130];
    __shared__ int sNR[2], sAF[2], sAL[2];

    const int tid = threadIdx.x;
    const int tx = tid & 15;
    const int ty = tid >> 4;
    const int wid = tid >> 6;
    const int lane = tid & 63;

    #pragma unroll 4
    for (int it = 0; it < 8; ++it)
        ((float4*)sW)[it * 512 + tid] = ((const float4*)We2)[it * 512 + tid];

    const float4 c0 = *(const float4*)&be2[ 0 + tx * 4];
    const float4 c1 = *(const float4*)&be2[64 + tx * 4];

    for (int t = blockIdx.x; t < NT; t += gridDim.x) {
        const int e0 = t * TILE;
        __syncthreads();                     // sW ready / prior tile done
        if (tid < 256)
            sDest[tid] = clampi(eidx[N_EDGES + g_perm[e0 + tid]], N_NODES);
        __syncthreads();

        if (tid < 2) {                       // run detection, one lane per subtile
            const int base = tid * 128;
            int prev;
            if (base == 0)
                prev = (e0 > 0) ? clampi(eidx[N_EDGES + g_perm[e0 - 1]], N_NODES) : -1;
            else
                prev = sDest[base - 1];
            sAF[tid] = (prev == sDest[base]) ? 1 : 0;
            int n = 0;
            for (int i = 0; i < 128; ++i) {
                int d = sDest[base + i];
                if (i == 0 || d != sDest[base + i - 1]) sRunS[tid][n++] = base + i;
            }
            sRunS[tid][n] = base + 128;
            sNR[tid] = n;
            int nxt;
            if (base + 128 == 256)
                nxt = (e0 + 256 < N_EDGES) ? clampi(eidx[N_EDGES + g_perm[e0 + 256]], N_NODES) : -1;
            else
                nxt = sDest[128];
            sAL[tid] = (nxt == sDest[base + 127]) ? 1 : 0;
        }

        float acc[8][8];
        #pragma unroll
        for (int r = 0; r < 8; ++r)
            #pragma unroll
            for (int c = 0; c < 8; ++c) acc[r][c] = 0.f;

        {
            const float* bp[8];
            #pragma unroll
            for (int r = 0; r < 8; ++r) bp[r] = g_h + (size_t)(e0 + ty * 8 + r) * 128;
            gemm_seg<0, 32, 128, 64>(sW, tx, bp, acc);
        }

        #pragma unroll 1
        for (int g2 = 0; g2 < 2; ++g2) {
            __syncthreads();                 // prior subtile reads done / runs ready
            if ((ty >> 4) == g2) {           // 16 ty groups own this 128-row subtile
                const int lr = (ty & 15) * 8;
                #pragma unroll
                for (int r = 0; r < 8; ++r) {
                    float4 v;
                    v.x = fmaxf(acc[r][0] + c0.x, 0.f); v.y = fmaxf(acc[r][1] + c0.y, 0.f);
                    v.z = fmaxf(acc[r][2] + c0.z, 0.f); v.w = fmaxf(acc[r][3] + c0.w, 0.f);
                    *(float4*)&sRed[lr + r][ 0 + tx * 4] = v;
                    v.x = fmaxf(acc[r][4] + c1.x, 0.f); v.y = fmaxf(acc[r][5] + c1.y, 0.f);
                    v.z = fmaxf(acc[r][6] + c1.z, 0.f); v.w = fmaxf(acc[r][7] + c1.w, 0.f);
                    *(float4*)&sRed[lr + r][64 + tx * 4] = v;
                }
            }
            __syncthreads();
            const int nR = sNR[g2];
            for (int m = wid; m < nR; m += 8) {   // one wave per run
                const int s = sRunS[g2][m]     - g2 * 128;
                const int e = sRunS[g2][m + 1] - g2 * 128;
                float v0 = 0.f, v1 = 0.f;
                for (int r = s; r < e; ++r) { v0 += sRed[r][lane]; v1 += sRed[r][lane + 64]; }
                const int d = sDest[g2 * 128 + s];
                float* dst = agg + (size_t)d * 128;
                const bool atom = (m == 0 && sAF[g2]) || (m == nR - 1 && sAL[g2]);
                if (atom) {
                    unsafeAtomicAdd(dst + lane,      v0);
                    unsafeAtomicAdd(dst + lane + 64, v1);
                } else {
                    dst[lane]      = v0;         // exclusive owner of this dest
                    dst[lane + 64] = v1;
                }
            }
        }
    }
}

// ---------------------------------------------------------------------------
// Fused node+global kernel (unchanged): one block (256 threads) per graph.
// ---------------------------------------------------------------------------
__global__ __launch_bounds__(256) void node_global_kernel(
    const float* __restrict__ x, const float* __restrict__ agg,
    const int* __restrict__ batch,
    const float* __restrict__ Wg, const float* __restrict__ bg,
    const float* __restrict__ Wn, const float* __restrict__ bn,
    const float* __restrict__ u, const float* __restrict__ Wu,
    const float* __restrict__ bu,
    float* __restrict__ xw_out, float* __restrict__ out)
{
    __shared__ alignas(16) float sA[32][260];
    __shared__ alignas(16) float sW[32][128];
    __shared__ alignas(16) float redu[16][132];
    __shared__ alignas(16) float cat[192];
    __shared__ int sRange[2];

    const int tid = threadIdx.x;
    const int tx = tid & 15;
    const int ty = tid >> 4;
    const int g = blockIdx.x;

    if (tid == 0) {
        int lo = 0, hi = N_NODES;
        while (lo < hi) { int m = (lo + hi) >> 1; if (batch[m] < g) lo = m + 1; else hi = m; }
        sRange[0] = lo;
        hi = N_NODES;
        while (lo < hi) { int m = (lo + hi) >> 1; if (batch[m] < g + 1) lo = m + 1; else hi = m; }
        sRange[1] = lo;
    }
    __syncthreads();
    const int start = sRange[0];
    const int end   = sRange[1];

    float pool_acc[8];
    #pragma unroll
    for (int j = 0; j < 8; ++j) pool_acc[j] = 0.f;

    for (int n0 = start; n0 < end; n0 += 32) {
        #pragma unroll
        for (int it = 0; it < 4; ++it) {
            int idx = it * 256 + tid;
            int r = idx >> 5, c = idx & 31;
            float4 v = make_float4(0.f, 0.f, 0.f, 0.f);
            if (n0 + r < end) v = *(const float4*)&x[(size_t)(n0 + r) * 128 + c * 4];
            *(float4*)&sA[r][c * 4] = v;
        }
        #pragma unroll
        for (int it = 0; it < 4; ++it) {
            int idx = it * 256 + tid;
            int r = idx >> 5, c = idx & 31;
            float4 v = make_float4(0.f, 0.f, 0.f, 0.f);
            if (n0 + r < end) v = *(const float4*)&agg[(size_t)(n0 + r) * 128 + c * 4];
            *(float4*)&sA[r][128 + c * 4] = v;
        }

        float acc[2][8];
        #pragma unroll
        for (int i = 0; i < 2; ++i)
            #pragma unroll
            for (int j = 0; j < 8; ++j) acc[i][j] = 0.f;

        for (int kc = 0; kc < 8; ++kc) {
            __syncthreads();
            #pragma unroll
            for (int it = 0; it < 4; ++it) {
                int idx = it * 256 + tid;
                int r = idx >> 5, c4 = idx & 31;
                *(float4*)&sW[r][c4 * 4] = *(const float4*)&Wg[(size_t)(kc * 32 + r) * 128 + c4 * 4];
            }
            __syncthreads();
            #pragma unroll
            for (int k = 0; k < 32; ++k) {
                float4 w0 = *(float4*)&sW[k][tx * 8];
                float4 w1 = *(float4*)&sW[k][tx * 8 + 4];
                float w[8] = {w0.x, w0.y, w0.z, w0.w, w1.x, w1.y, w1.z, w1.w};
                float a0 = sA[ty * 2 + 0][kc * 32 + k];
                float a1 = sA[ty * 2 + 1][kc * 32 + k];
                #pragma unroll
                for (int j = 0; j < 8; ++j) {
                    acc[0][j] = fmaf(a0, w[j], acc[0][j]);
                    acc[1][j] = fmaf(a1, w[j], acc[1][j]);
                }
            }
        }

        float gate[2][8];
        #pragma unroll
        for (int i = 0; i < 2; ++i) {
            int n = n0 + ty * 2 + i;
            #pragma unroll
            for (int j = 0; j < 8; ++j) {
                float v = acc[i][j] + bg[tx * 8 + j];
                gate[i][j] = 1.0f / (1.0f + __expf(-v));
                acc[i][j] = 0.f;
            }
            if (n < end) {
                float4 g0 = make_float4(gate[i][0], gate[i][1], gate[i][2], gate[i][3]);
                float4 g1 = make_float4(gate[i][4], gate[i][5], gate[i][6], gate[i][7]);
                *(float4*)&xw_out[(size_t)n * 128 + tx * 8]     = g0;
                *(float4*)&xw_out[(size_t)n * 128 + tx * 8 + 4] = g1;
            }
        }

        for (int kc = 0; kc < 8; ++kc) {
            __syncthreads();
            #pragma unroll
            for (int it = 0; it < 4; ++it) {
                int idx = it * 256 + tid;
                int r = idx >> 5, c4 = idx & 31;
                *(float4*)&sW[r][c4 * 4] = *(const float4*)&Wn[(size_t)(kc * 32 + r) * 128 + c4 * 4];
            }
            __syncthreads();
            #pragma unroll
            for (int k = 0; k < 32; ++k) {
                float4 w0 = *(float4*)&sW[k][tx * 8];
                float4 w1 = *(float4*)&sW[k][tx * 8 + 4];
                float w[8] = {w0.x, w0.y, w0.z, w0.w, w1.x, w1.y, w1.z, w1.w};
                float a0 = sA[ty * 2 + 0][kc * 32 + k];
                float a1 = sA[ty * 2 + 1][kc * 32 + k];
                #pragma unroll
                for (int j = 0; j < 8; ++j) {
                    acc[0][j] = fmaf(a0, w[j], acc[0][j]);
                    acc[1][j] = fmaf(a1, w[j], acc[1][j]);
                }
            }
        }

        #pragma unroll
        for (int i = 0; i < 2; ++i) {
            int n = n0 + ty * 2 + i;
            if (n < end) {
                #pragma unroll
                for (int j = 0; j < 8; ++j) {
                    float v = fmaxf(acc[i][j] + bn[tx * 8 + j], 0.f);
                    pool_acc[j] += gate[i][j] * v;
                }
            }
        }
        __syncthreads();
    }

    #pragma unroll
    for (int j = 0; j < 8; ++j) redu[ty][tx * 8 + j] = pool_acc[j];
    __syncthreads();
    #pragma unroll
    for (int s = 8; s >= 1; s >>= 1) {
        if (ty < s) {
            #pragma unroll
            for (int j = 0; j < 8; ++j)
                redu[ty][tx * 8 + j] += redu[ty + s][tx * 8 + j];
        }
        __syncthreads();
    }

    float cnt = fmaxf((float)(end - start), 1.0f);
    if (tid < 64)        cat[tid] = u[g * 64 + tid];
    else if (tid < 192)  cat[tid] = redu[0][tid - 64] / cnt;
    __syncthreads();
    if (tid < 64) {
        float acc = bu[tid];
        #pragma unroll 4
        for (int k = 0; k < 192; ++k)
            acc = fmaf(cat[k], Wu[k * 64 + tid], acc);
        out[g * 64 + tid] = fmaxf(acc, 0.f);
    }
}

// ---------------------------------------------------------------------------
extern "C" void kernel_launch(void* const* d_in, const int* in_sizes, int n_in,
                              void* d_out, int out_size, void* d_ws, size_t ws_size,
                              hipStream_t stream) {
    const float* x     = (const float*)d_in[0];
    const int*   eidx  = (const int*)d_in[1];
    const float* eattr = (const float*)d_in[2];
    const float* u     = (const float*)d_in[3];
    const int*   batch = (const int*)d_in[4];
    const float* We1   = (const float*)d_in[5];
    const float* be1   = (const float*)d_in[6];
    const float* We2   = (const float*)d_in[7];
    const float* be2   = (const float*)d_in[8];
    const float* Wg    = (const float*)d_in[9];
    const float* bg    = (const float*)d_in[10];
    const float* Wn    = (const float*)d_in[11];
    const float* bn    = (const float*)d_in[12];
    const float* Wu    = (const float*)d_in[13];
    const float* bu    = (const float*)d_in[14];

    float* out    = (float*)d_out;                 // chunk 0: u_new [512*64] fp32
    float* xw_out = out + N_GRAPHS * D_GLOB;       // chunk 1: x_weights [50000*128] fp32
    float* agg    = xw_out;                        // fp32 agg aliases chunk 1

    // zero the agg region (d_out is re-poisoned before every timed launch)
    hipMemsetAsync(xw_out, 0, (size_t)N_NODES * D_HID * sizeof(float), stream);

    zero_counts_kernel<<<(N_NODES + 255) / 256, 256, 0, stream>>>();
    hist_kernel<<<(N_EDGES + 255) / 256, 256, 0, stream>>>(eidx);
    scan_kernel<<<1, 256, 0, stream>>>();
    scatter_kernel<<<(N_EDGES + 255) / 256, 256, 0, stream>>>(eidx);
    node_pre_kernel<<<256, 512, 0, stream>>>(x, We1);
    edge_h_kernel<<<2048, 256, 0, stream>>>(eidx, eattr, We1, be1);
    edge_l2_kernel<<<256, 512, 0, stream>>>(eidx, We2, be2, agg);
    node_global_kernel<<<N_GRAPHS, 256, 0, stream>>>(x, agg, batch, Wg, bg, Wn, bn,
                                                     u, Wu, bu, xw_out, out);
}

// Round 5
// 1026.657 us; speedup vs baseline: 5.0103x; 1.3660x over previous
//
#include <hip/hip_runtime.h>

#define N_NODES 50000
#define N_EDGES 800000
#define N_GRAPHS 512
#define D_IN 128
#define D_EDGE 32
#define D_HID 128
#define D_GLOB 64
#define NTF (N_EDGES / 128)          // 6250 fused edge tiles of 128 edges
#define NTP ((N_NODES + 127) / 128)  // 391 node_pre tiles
#define NTN ((N_NODES + 255) / 256)  // 196 node gate/upd tiles

// Static device scratch (zero-init .bss at module load).
__device__ float g_xab[(size_t)N_NODES * 256];    // 51.2 MB: [xa | xb] per node
__device__ float g_agg[(size_t)N_NODES * D_HID];  // 25.6 MB: aggregated messages
__device__ float g_pooled[N_GRAPHS * D_HID];      // 256 KB: per-graph pooled sums
__device__ int g_counts[N_NODES];
__device__ int g_cursor[N_NODES];
__device__ int g_perm[N_EDGES];

__device__ __forceinline__ int clampi(int v, int hi) {   // [0, hi)
    return v < 0 ? 0 : (v >= hi ? hi - 1 : v);
}

// ---------------------------------------------------------------------------
// Zero scratch that must be fresh every launch (g_agg gets boundary atomics;
// g_pooled is pure-atomic; g_counts is the sort histogram).
// ---------------------------------------------------------------------------
__global__ void zero_aux_kernel()
{
    const size_t i = (size_t)blockIdx.x * 256 + threadIdx.x;
    const float4 z = make_float4(0.f, 0.f, 0.f, 0.f);
    if (i < (size_t)N_NODES * 32) ((float4*)g_agg)[i] = z;
    if (i < N_GRAPHS * 32)        ((float4*)g_pooled)[i] = z;
    if (i < N_NODES)              g_counts[i] = 0;
}

// ---------------------------------------------------------------------------
// Counting-sort of edges by destination node.
// ---------------------------------------------------------------------------
__global__ void hist_kernel(const int* __restrict__ eidx)
{
    int e = blockIdx.x * 256 + threadIdx.x;
    if (e < N_EDGES) atomicAdd(&g_counts[clampi(eidx[N_EDGES + e], N_NODES)], 1);
}

// LDS-staged coalesced exclusive scan (replaces serial strided version).
#define SCAN_HALF 25088   // 256 * 98
#define SCAN_CH 98
__global__ __launch_bounds__(512) void scan_kernel()
{
    __shared__ int buf[SCAN_HALF];   // 100352 B
    __shared__ int part[512];
    const int t = threadIdx.x;

    #pragma unroll 1
    for (int p = 0; p < 2; ++p) {
        const int base = p * SCAN_HALF;
        __syncthreads();
        for (int i = t; i < SCAN_HALF; i += 512) {
            int gg = base + i;
            buf[i] = (gg < N_NODES) ? g_counts[gg] : 0;
        }
        __syncthreads();
        if ((t >> 8) == p) {
            const int l0 = t * SCAN_CH - base;
            int s = 0;
            for (int i = 0; i < SCAN_CH; ++i) s += buf[l0 + i];
            part[t] = s;
        }
    }
    __syncthreads();
    if (t == 0) {
        int run = 0;
        for (int i = 0; i < 512; ++i) { int v = part[i]; part[i] = run; run += v; }
    }
    #pragma unroll 1
    for (int p = 0; p < 2; ++p) {
        const int base = p * SCAN_HALF;
        __syncthreads();
        for (int i = t; i < SCAN_HALF; i += 512) {
            int gg = base + i;
            buf[i] = (gg < N_NODES) ? g_counts[gg] : 0;
        }
        __syncthreads();
        if ((t >> 8) == p) {
            const int l0 = t * SCAN_CH - base;
            int run = part[t];
            for (int i = 0; i < SCAN_CH; ++i) { int v = buf[l0 + i]; buf[l0 + i] = run; run += v; }
        }
        __syncthreads();
        for (int i = t; i < SCAN_HALF; i += 512) {
            int gg = base + i;
            if (gg < N_NODES) g_cursor[gg] = buf[i];
        }
    }
}

__global__ void scatter_kernel(const int* __restrict__ eidx)
{
    int e = blockIdx.x * 256 + threadIdx.x;
    if (e < N_EDGES) {
        int d = clampi(eidx[N_EDGES + e], N_NODES);
        int p = atomicAdd(&g_cursor[d], 1);
        g_perm[p] = e;
    }
}

// ---------------------------------------------------------------------------
// Register-tile GEMM core (R rows x 8 cols per thread). A streams from
// global/LDS into double-buffered registers; W is LDS-resident with leading
// dim LD and second-column-group offset OFF. Conflict-free b128 reads.
// ---------------------------------------------------------------------------
template<int R, int KBASE, int LD, int OFF>
__device__ __forceinline__ void step4(const float* __restrict__ sW, int kg, int tx,
                                      const float4 (&a)[R], float (&acc)[R][8])
{
    #pragma unroll
    for (int kk = 0; kk < 4; ++kk) {
        const float* wr = sW + (size_t)(KBASE + kg * 4 + kk) * LD + tx * 4;
        float4 w0 = *(const float4*)(wr);
        float4 w1 = *(const float4*)(wr + OFF);
        #pragma unroll
        for (int r = 0; r < R; ++r) {
            const float av = ((const float*)&a[r])[kk];
            acc[r][0] = fmaf(av, w0.x, acc[r][0]);
            acc[r][1] = fmaf(av, w0.y, acc[r][1]);
            acc[r][2] = fmaf(av, w0.z, acc[r][2]);
            acc[r][3] = fmaf(av, w0.w, acc[r][3]);
            acc[r][4] = fmaf(av, w1.x, acc[r][4]);
            acc[r][5] = fmaf(av, w1.y, acc[r][5]);
            acc[r][6] = fmaf(av, w1.z, acc[r][6]);
            acc[r][7] = fmaf(av, w1.w, acc[r][7]);
        }
    }
}

template<int R, int KBASE, int KG, int LD, int OFF>
__device__ __forceinline__ void gemm_seg(const float* __restrict__ sW, int tx,
                                         const float* const (&bp)[R],
                                         float (&acc)[R][8])
{
    float4 a0[R], a1[R];
    #pragma unroll
    for (int r = 0; r < R; ++r) a0[r] = *(const float4*)(bp[r]);
    #pragma unroll 1
    for (int kg = 0; kg < KG; kg += 2) {
        #pragma unroll
        for (int r = 0; r < R; ++r) a1[r] = *(const float4*)(bp[r] + (kg + 1) * 4);
        step4<R, KBASE, LD, OFF>(sW, kg, tx, a0, acc);
        if (kg + 2 < KG) {
            #pragma unroll
            for (int r = 0; r < R; ++r) a0[r] = *(const float4*)(bp[r] + (kg + 2) * 4);
        }
        step4<R, KBASE, LD, OFF>(sW, kg + 1, tx, a1, acc);
    }
}

// ---------------------------------------------------------------------------
// Node precompute: xab[n] = x[n] @ [We1_top | We1_bot]  (unchanged, r4-proven)
// ---------------------------------------------------------------------------
__global__ __launch_bounds__(512, 2) void node_pre_kernel(
    const float* __restrict__ x, const float* __restrict__ We1)
{
    __shared__ float sWp[128 * 256];     // 131072 B
    const int tid = threadIdx.x;
    const int tx = tid & 31;
    const int ty = tid >> 5;

    #pragma unroll 4
    for (int it = 0; it < 16; ++it) {
        int idx = it * 512 + tid;        // float4 index, 8192 total
        int k = idx >> 6;
        int c = (idx & 63) * 4;
        const float* src = (c < 128) ? (We1 + (size_t)k * 128 + c)
                                     : (We1 + (size_t)(128 + k) * 128 + (c - 128));
        *(float4*)&sWp[(size_t)idx * 4] = *(const float4*)src;
    }
    __syncthreads();

    for (int t = blockIdx.x; t < NTP; t += gridDim.x) {
        const int n0 = t * 128;
        float acc[8][8];
        #pragma unroll
        for (int r = 0; r < 8; ++r)
            #pragma unroll
            for (int c = 0; c < 8; ++c) acc[r][c] = 0.f;

        const float* bp[8];
        #pragma unroll
        for (int r = 0; r < 8; ++r) {
            int n = n0 + ty * 8 + r;
            if (n >= N_NODES) n = N_NODES - 1;
            bp[r] = x + (size_t)n * 128;
        }
        gemm_seg<8, 0, 32, 256, 128>(sWp, tx, bp, acc);

        #pragma unroll
        for (int r = 0; r < 8; ++r) {
            int n = n0 + ty * 8 + r;
            if (n < N_NODES) {
                float* dst = g_xab + (size_t)n * 256;
                *(float4*)(dst + tx * 4)       = make_float4(acc[r][0], acc[r][1], acc[r][2], acc[r][3]);
                *(float4*)(dst + 128 + tx * 4) = make_float4(acc[r][4], acc[r][5], acc[r][6], acc[r][7]);
            }
        }
    }
}

// ---------------------------------------------------------------------------
// Fused edge kernel: per 128-edge (dest-sorted) tile:
//  ph1: h = relu(xa[src]+xb[dst] + attr@W1c + be1) -> LDS sH (own rows/wave)
//  ph2: msg GEMM vs LDS-resident We2 (K=128), A read from sH (same-wave RAW,
//       DS ops are in-order per wave -> no barrier needed)
//  ph3: msg = relu(.+be2) overwrites sH
//  ph4: run-segmented reduce -> g_agg; atomics only at 64-row-subtile edges.
// LDS: 16K(W1c)+64K(We2)+67.6K(sH)+~3K = ~151 KB -> 1 block/CU, 8 waves.
// ---------------------------------------------------------------------------
__global__ __launch_bounds__(512, 2) void edge_fused_kernel(
    const int* __restrict__ eidx, const float* __restrict__ eattr,
    const float* __restrict__ We1, const float* __restrict__ be1,
    const float* __restrict__ We2, const float* __restrict__ be2)
{
    __shared__ float sWc[32 * 128];      // 16384 B: We1 rows 256..288
    __shared__ float sW2[128 * 128];     // 65536 B
    __shared__ float sH[128 * 132];      // 67584 B (pad 132: conflict-free)
    __shared__ int sSrc[128], sDst[128], sEdg[128];
    __shared__ int sRunS[2][65];
    __shared__ int sNR[2], sAF[2], sAL[2];

    const int tid = threadIdx.x;
    const int tx = tid & 15;
    const int ty = tid >> 4;             // [0,32), 4 rows each
    const int wid = tid >> 6;
    const int lane = tid & 63;

    #pragma unroll
    for (int it = 0; it < 2; ++it)
        ((float4*)sWc)[it * 512 + tid] = ((const float4*)(We1 + (size_t)256 * 128))[it * 512 + tid];
    #pragma unroll 4
    for (int it = 0; it < 8; ++it)
        ((float4*)sW2)[it * 512 + tid] = ((const float4*)We2)[it * 512 + tid];

    const float4 b0 = *(const float4*)&be1[tx * 4];
    const float4 b1 = *(const float4*)&be1[64 + tx * 4];
    const float4 c0 = *(const float4*)&be2[tx * 4];
    const float4 c1 = *(const float4*)&be2[64 + tx * 4];

    for (int t = blockIdx.x; t < NTF; t += gridDim.x) {
        const int e0 = t * 128;
        __syncthreads();                 // weights ready / prior reduce done
        if (tid < 128) {
            int p = g_perm[e0 + tid];
            sEdg[tid] = p;
            sSrc[tid] = clampi(eidx[p], N_NODES);
            sDst[tid] = clampi(eidx[N_EDGES + p], N_NODES);
        }
        __syncthreads();

        // ---- phase 1: h rows (xa + xb + attr@W1c) ----
        float acc[4][8];
        #pragma unroll
        for (int r = 0; r < 4; ++r) {
            const int row = ty * 4 + r;
            const float* pa = g_xab + (size_t)sSrc[row] * 256 + tx * 4;
            const float* pb = g_xab + (size_t)sDst[row] * 256 + 128 + tx * 4;
            float4 xa0 = *(const float4*)(pa);
            float4 xa1 = *(const float4*)(pa + 64);
            float4 xb0 = *(const float4*)(pb);
            float4 xb1 = *(const float4*)(pb + 64);
            acc[r][0] = xa0.x + xb0.x; acc[r][1] = xa0.y + xb0.y;
            acc[r][2] = xa0.z + xb0.z; acc[r][3] = xa0.w + xb0.w;
            acc[r][4] = xa1.x + xb1.x; acc[r][5] = xa1.y + xb1.y;
            acc[r][6] = xa1.z + xb1.z; acc[r][7] = xa1.w + xb1.w;
        }
        #pragma unroll 1
        for (int kg = 0; kg < 8; ++kg) {
            float4 av[4];
            #pragma unroll
            for (int r = 0; r < 4; ++r)
                av[r] = *(const float4*)(eattr + (size_t)sEdg[ty * 4 + r] * 32 + kg * 4);
            #pragma unroll
            for (int kk = 0; kk < 4; ++kk) {
                const float* wr = sWc + (size_t)(kg * 4 + kk) * 128 + tx * 4;
                float4 w0 = *(const float4*)(wr);
                float4 w1 = *(const float4*)(wr + 64);
                #pragma unroll
                for (int r = 0; r < 4; ++r) {
                    const float a = ((const float*)&av[r])[kk];
                    acc[r][0] = fmaf(a, w0.x, acc[r][0]);
                    acc[r][1] = fmaf(a, w0.y, acc[r][1]);
                    acc[r][2] = fmaf(a, w0.z, acc[r][2]);
                    acc[r][3] = fmaf(a, w0.w, acc[r][3]);
                    acc[r][4] = fmaf(a, w1.x, acc[r][4]);
                    acc[r][5] = fmaf(a, w1.y, acc[r][5]);
                    acc[r][6] = fmaf(a, w1.z, acc[r][6]);
                    acc[r][7] = fmaf(a, w1.w, acc[r][7]);
                }
            }
        }
        #pragma unroll
        for (int r = 0; r < 4; ++r) {
            const int row = ty * 4 + r;
            float4 v;
            v.x = fmaxf(acc[r][0] + b0.x, 0.f); v.y = fmaxf(acc[r][1] + b0.y, 0.f);
            v.z = fmaxf(acc[r][2] + b0.z, 0.f); v.w = fmaxf(acc[r][3] + b0.w, 0.f);
            *(float4*)&sH[row * 132 + tx * 4] = v;
            v.x = fmaxf(acc[r][4] + b1.x, 0.f); v.y = fmaxf(acc[r][5] + b1.y, 0.f);
            v.z = fmaxf(acc[r][6] + b1.z, 0.f); v.w = fmaxf(acc[r][7] + b1.w, 0.f);
            *(float4*)&sH[row * 132 + 64 + tx * 4] = v;
        }

        // ---- phase 2: msg GEMM (A rows owned by this wave; DS in-order) ----
        float acc2[4][8];
        #pragma unroll
        for (int r = 0; r < 4; ++r)
            #pragma unroll
            for (int c = 0; c < 8; ++c) acc2[r][c] = 0.f;
        {
            const float* bp[4];
            #pragma unroll
            for (int r = 0; r < 4; ++r) bp[r] = &sH[(ty * 4 + r) * 132];
            gemm_seg<4, 0, 32, 128, 64>(sW2, tx, bp, acc2);
        }

        // ---- phase 3: msg = relu(.+be2) overwrites sH (own rows) ----
        #pragma unroll
        for (int r = 0; r < 4; ++r) {
            const int row = ty * 4 + r;
            float4 v;
            v.x = fmaxf(acc2[r][0] + c0.x, 0.f); v.y = fmaxf(acc2[r][1] + c0.y, 0.f);
            v.z = fmaxf(acc2[r][2] + c0.z, 0.f); v.w = fmaxf(acc2[r][3] + c0.w, 0.f);
            *(float4*)&sH[row * 132 + tx * 4] = v;
            v.x = fmaxf(acc2[r][4] + c1.x, 0.f); v.y = fmaxf(acc2[r][5] + c1.y, 0.f);
            v.z = fmaxf(acc2[r][6] + c1.z, 0.f); v.w = fmaxf(acc2[r][7] + c1.w, 0.f);
            *(float4*)&sH[row * 132 + 64 + tx * 4] = v;
        }

        // run detection (2 lanes; hidden behind other waves' compute)
        if (tid < 2) {
            const int base = tid * 64;
            int prev = (base == 0)
                ? ((e0 > 0) ? clampi(eidx[N_EDGES + g_perm[e0 - 1]], N_NODES) : -1)
                : sDst[63];
            sAF[tid] = (prev == sDst[base]) ? 1 : 0;
            int n = 0;
            for (int i = 0; i < 64; ++i) {
                int d = sDst[base + i];
                if (i == 0 || d != sDst[base + i - 1]) sRunS[tid][n++] = base + i;
            }
            sRunS[tid][n] = base + 64;
            sNR[tid] = n;
            int nxt = (base == 64)
                ? ((e0 + 128 < N_EDGES) ? clampi(eidx[N_EDGES + g_perm[e0 + 128]], N_NODES) : -1)
                : sDst[64];
            sAL[tid] = (nxt == sDst[base + 63]) ? 1 : 0;
        }
        __syncthreads();

        // ---- phase 4: segmented reduce -> g_agg ----
        #pragma unroll 1
        for (int g2 = 0; g2 < 2; ++g2) {
            const int nR = sNR[g2];
            for (int m = wid; m < nR; m += 8) {      // one wave per run
                const int s = sRunS[g2][m];
                const int e = sRunS[g2][m + 1];
                float v0 = 0.f, v1 = 0.f;
                for (int r = s; r < e; ++r) { v0 += sH[r * 132 + lane]; v1 += sH[r * 132 + 64 + lane]; }
                const int d = sDst[s];
                float* dst = g_agg + (size_t)d * 128;
                const bool atom = (m == 0 && sAF[g2]) || (m == nR - 1 && sAL[g2]);
                if (atom) {
                    unsafeAtomicAdd(dst + lane,      v0);
                    unsafeAtomicAdd(dst + lane + 64, v1);
                } else {
                    dst[lane]      = v0;             // exclusive owner
                    dst[lane + 64] = v1;
                }
            }
        }
    }
}

// ---------------------------------------------------------------------------
// Node gate: x_weights[n] = sigmoid([x[n]|agg[n]] @ Wg + bg). Wg LDS-resident
// (128 KB), 256-node tiles, one tile per block.
// ---------------------------------------------------------------------------
__global__ __launch_bounds__(512, 2) void node_gate_kernel(
    const float* __restrict__ x, const float* __restrict__ Wg,
    const float* __restrict__ bg, float* __restrict__ xw_out)
{
    __shared__ float sW[256 * 128];      // 131072 B
    const int tid = threadIdx.x;
    const int tx = tid & 15;
    const int ty = tid >> 4;

    #pragma unroll 4
    for (int it = 0; it < 16; ++it)
        ((float4*)sW)[it * 512 + tid] = ((const float4*)Wg)[it * 512 + tid];
    __syncthreads();

    const float4 b0 = *(const float4*)&bg[tx * 4];
    const float4 b1 = *(const float4*)&bg[64 + tx * 4];
    const int n0 = blockIdx.x * 256;

    float acc[8][8];
    #pragma unroll
    for (int r = 0; r < 8; ++r)
        #pragma unroll
        for (int c = 0; c < 8; ++c) acc[r][c] = 0.f;

    const float* bp[8];
    #pragma unroll
    for (int r = 0; r < 8; ++r) {
        int n = n0 + ty * 8 + r; if (n >= N_NODES) n = N_NODES - 1;
        bp[r] = x + (size_t)n * 128;
    }
    gemm_seg<8, 0, 32, 128, 64>(sW, tx, bp, acc);
    #pragma unroll
    for (int r = 0; r < 8; ++r) {
        int n = n0 + ty * 8 + r; if (n >= N_NODES) n = N_NODES - 1;
        bp[r] = g_agg + (size_t)n * 128;
    }
    gemm_seg<8, 128, 32, 128, 64>(sW, tx, bp, acc);

    #pragma unroll
    for (int r = 0; r < 8; ++r) {
        const int n = n0 + ty * 8 + r;
        if (n < N_NODES) {
            float4 v;
            v.x = 1.f / (1.f + __expf(-(acc[r][0] + b0.x)));
            v.y = 1.f / (1.f + __expf(-(acc[r][1] + b0.y)));
            v.z = 1.f / (1.f + __expf(-(acc[r][2] + b0.z)));
            v.w = 1.f / (1.f + __expf(-(acc[r][3] + b0.w)));
            *(float4*)&xw_out[(size_t)n * 128 + tx * 4] = v;
            v.x = 1.f / (1.f + __expf(-(acc[r][4] + b1.x)));
            v.y = 1.f / (1.f + __expf(-(acc[r][5] + b1.y)));
            v.z = 1.f / (1.f + __expf(-(acc[r][6] + b1.z)));
            v.w = 1.f / (1.f + __expf(-(acc[r][7] + b1.w)));
            *(float4*)&xw_out[(size_t)n * 128 + 64 + tx * 4] = v;
        }
    }
}

// ---------------------------------------------------------------------------
// Node update: x_new = gate * relu([x|agg] @ Wn + bn); pooled[g] += x_new via
// in-register run segments (batch sorted) + scalar atomics.
// ---------------------------------------------------------------------------
__global__ __launch_bounds__(512, 2) void node_upd_kernel(
    const float* __restrict__ x, const int* __restrict__ batch,
    const float* __restrict__ Wn, const float* __restrict__ bn,
    const float* __restrict__ xw_out)
{
    __shared__ float sW[256 * 128];      // 131072 B
    __shared__ int sB[256];
    const int tid = threadIdx.x;
    const int tx = tid & 15;
    const int ty = tid >> 4;
    const int n0 = blockIdx.x * 256;

    #pragma unroll 4
    for (int it = 0; it < 16; ++it)
        ((float4*)sW)[it * 512 + tid] = ((const float4*)Wn)[it * 512 + tid];
    if (tid < 256) {
        int n = n0 + tid;
        sB[tid] = (n < N_NODES) ? batch[n] : -2;
    }
    __syncthreads();

    const float4 b0 = *(const float4*)&bn[tx * 4];
    const float4 b1 = *(const float4*)&bn[64 + tx * 4];

    float acc[8][8];
    #pragma unroll
    for (int r = 0; r < 8; ++r)
        #pragma unroll
        for (int c = 0; c < 8; ++c) acc[r][c] = 0.f;

    const float* bp[8];
    #pragma unroll
    for (int r = 0; r < 8; ++r) {
        int n = n0 + ty * 8 + r; if (n >= N_NODES) n = N_NODES - 1;
        bp[r] = x + (size_t)n * 128;
    }
    gemm_seg<8, 0, 32, 128, 64>(sW, tx, bp, acc);
    #pragma unroll
    for (int r = 0; r < 8; ++r) {
        int n = n0 + ty * 8 + r; if (n >= N_NODES) n = N_NODES - 1;
        bp[r] = g_agg + (size_t)n * 128;
    }
    gemm_seg<8, 128, 32, 128, 64>(sW, tx, bp, acc);

    float ps[8];
    int cg = -1;
    #pragma unroll
    for (int r = 0; r < 8; ++r) {
        const int n = n0 + ty * 8 + r;
        const bool ok = (n < N_NODES);
        if (ok) {
            const float4 ga = *(const float4*)&xw_out[(size_t)n * 128 + tx * 4];
            const float4 gb = *(const float4*)&xw_out[(size_t)n * 128 + 64 + tx * 4];
            float v[8];
            v[0] = ga.x * fmaxf(acc[r][0] + b0.x, 0.f);
            v[1] = ga.y * fmaxf(acc[r][1] + b0.y, 0.f);
            v[2] = ga.z * fmaxf(acc[r][2] + b0.z, 0.f);
            v[3] = ga.w * fmaxf(acc[r][3] + b0.w, 0.f);
            v[4] = gb.x * fmaxf(acc[r][4] + b1.x, 0.f);
            v[5] = gb.y * fmaxf(acc[r][5] + b1.y, 0.f);
            v[6] = gb.z * fmaxf(acc[r][6] + b1.z, 0.f);
            v[7] = gb.w * fmaxf(acc[r][7] + b1.w, 0.f);
            const int gph = sB[ty * 8 + r];
            if (gph != cg) {
                if (cg >= 0) {
                    #pragma unroll
                    for (int j = 0; j < 4; ++j)
                        unsafeAtomicAdd(&g_pooled[(size_t)cg * 128 + tx * 4 + j], ps[j]);
                    #pragma unroll
                    for (int j = 0; j < 4; ++j)
                        unsafeAtomicAdd(&g_pooled[(size_t)cg * 128 + 64 + tx * 4 + j], ps[4 + j]);
                }
                cg = gph;
                #pragma unroll
                for (int j = 0; j < 8; ++j) ps[j] = v[j];
            } else {
                #pragma unroll
                for (int j = 0; j < 8; ++j) ps[j] += v[j];
            }
        }
    }
    if (cg >= 0) {
        #pragma unroll
        for (int j = 0; j < 4; ++j)
            unsafeAtomicAdd(&g_pooled[(size_t)cg * 128 + tx * 4 + j], ps[j]);
        #pragma unroll
        for (int j = 0; j < 4; ++j)
            unsafeAtomicAdd(&g_pooled[(size_t)cg * 128 + 64 + tx * 4 + j], ps[4 + j]);
    }
}

// ---------------------------------------------------------------------------
// Global block: u_new[g] = relu([u[g] | pooled[g]/cnt] @ Wu + bu).
// ---------------------------------------------------------------------------
__global__ __launch_bounds__(64) void global_kernel(
    const int* __restrict__ batch, const float* __restrict__ u,
    const float* __restrict__ Wu, const float* __restrict__ bu,
    float* __restrict__ out)
{
    __shared__ float cat[192];
    __shared__ int sRange[2];
    const int g = blockIdx.x;
    const int t = threadIdx.x;

    if (t == 0) {
        int lo = 0, hi = N_NODES;
        while (lo < hi) { int m = (lo + hi) >> 1; if (batch[m] < g) lo = m + 1; else hi = m; }
        sRange[0] = lo;
        hi = N_NODES;
        while (lo < hi) { int m = (lo + hi) >> 1; if (batch[m] < g + 1) lo = m + 1; else hi = m; }
        sRange[1] = lo;
    }
    __syncthreads();
    const float cnt = fmaxf((float)(sRange[1] - sRange[0]), 1.0f);

    cat[t] = u[g * 64 + t];
    #pragma unroll
    for (int i = 0; i < 2; ++i)
        cat[64 + i * 64 + t] = g_pooled[g * 128 + i * 64 + t] / cnt;
    __syncthreads();

    float acc = bu[t];
    #pragma unroll 4
    for (int k = 0; k < 192; ++k)
        acc = fmaf(cat[k], Wu[k * 64 + t], acc);
    out[g * 64 + t] = fmaxf(acc, 0.f);
}

// ---------------------------------------------------------------------------
extern "C" void kernel_launch(void* const* d_in, const int* in_sizes, int n_in,
                              void* d_out, int out_size, void* d_ws, size_t ws_size,
                              hipStream_t stream) {
    const float* x     = (const float*)d_in[0];
    const int*   eidx  = (const int*)d_in[1];
    const float* eattr = (const float*)d_in[2];
    const float* u     = (const float*)d_in[3];
    const int*   batch = (const int*)d_in[4];
    const float* We1   = (const float*)d_in[5];
    const float* be1   = (const float*)d_in[6];
    const float* We2   = (const float*)d_in[7];
    const float* be2   = (const float*)d_in[8];
    const float* Wg    = (const float*)d_in[9];
    const float* bg    = (const float*)d_in[10];
    const float* Wn    = (const float*)d_in[11];
    const float* bn    = (const float*)d_in[12];
    const float* Wu    = (const float*)d_in[13];
    const float* bu    = (const float*)d_in[14];

    float* out    = (float*)d_out;                 // chunk 0: u_new [512*64] fp32
    float* xw_out = out + N_GRAPHS * D_GLOB;       // chunk 1: x_weights [50000*128] fp32

    zero_aux_kernel<<<6250, 256, 0, stream>>>();
    hist_kernel<<<(N_EDGES + 255) / 256, 256, 0, stream>>>(eidx);
    scan_kernel<<<1, 512, 0, stream>>>();
    scatter_kernel<<<(N_EDGES + 255) / 256, 256, 0, stream>>>(eidx);
    node_pre_kernel<<<196, 512, 0, stream>>>(x, We1);
    edge_fused_kernel<<<250, 512, 0, stream>>>(eidx, eattr, We1, be1, We2, be2);
    node_gate_kernel<<<NTN, 512, 0, stream>>>(x, Wg, bg, xw_out);
    node_upd_kernel<<<NTN, 512, 0, stream>>>(x, batch, Wn, bn, xw_out);
    global_kernel<<<N_GRAPHS, 64, 0, stream>>>(batch, u, Wu, bu, out);
}